// Round 1
// baseline (5850.807 us; speedup 1.0000x reference)
//
#include <hip/hip_runtime.h>
#include <hip/hip_bf16.h>
#include <math.h>

// Problem constants
#define Bn   64
#define Ssz  512     // W*H = 64*8
#define Ed   192
#define NHd  6
#define HDd  32
#define Ld   6
#define COd  256
#define Himg 8
#define Wimg 64
#define Mrows (Bn*Ssz)   // 32768

// ---------------------------------------------------------------------------
// reshape: image [B, E, 8, 64] -> X [B, S=w*8+h, E]
__global__ __launch_bounds__(256) void reshape_in(const float* __restrict__ img,
                                                  float* __restrict__ X) {
    int t = blockIdx.x * 256 + threadIdx.x;           // 6,291,456 total
    int c = t % Ed;
    int s = (t / Ed) % Ssz;
    int b = t / (Ed * Ssz);
    int w = s >> 3, h = s & 7;
    X[t] = img[(((size_t)b * Ed + c) * Himg + h) * Wimg + w];
}

// ---------------------------------------------------------------------------
// LayerNorm over E=192, one wave (64 lanes) per row, 3 elems/lane.
__global__ __launch_bounds__(256) void ln_kernel(const float* __restrict__ in,
                                                 float* __restrict__ out,
                                                 const float* __restrict__ g,
                                                 const float* __restrict__ bb) {
    int row  = blockIdx.x * 4 + (threadIdx.x >> 6);
    int lane = threadIdx.x & 63;
    const float* x = in + (size_t)row * Ed;
    float v0 = x[lane], v1 = x[lane + 64], v2 = x[lane + 128];
    float s = v0 + v1 + v2;
    #pragma unroll
    for (int off = 32; off > 0; off >>= 1) s += __shfl_xor(s, off);
    float mu = s * (1.f / 192.f);
    float d0 = v0 - mu, d1 = v1 - mu, d2 = v2 - mu;
    float q = d0*d0 + d1*d1 + d2*d2;
    #pragma unroll
    for (int off = 32; off > 0; off >>= 1) q += __shfl_xor(q, off);
    float rstd = rsqrtf(q * (1.f / 192.f) + 1e-5f);
    float* o = out + (size_t)row * Ed;
    o[lane]       = d0 * rstd * g[lane]       + bb[lane];
    o[lane + 64]  = d1 * rstd * g[lane + 64]  + bb[lane + 64];
    o[lane + 128] = d2 * rstd * g[lane + 128] + bb[lane + 128];
}

// ---------------------------------------------------------------------------
// fp32 GEMM: C[M,N] = A[M,K] @ Wt[N,K]^T + bias (+ relu) (+ resid)
// BM=128, BN=64, BK=16, 256 threads, 8x4 per thread. N%64==0, M%128==0, K%16==0.
__global__ __launch_bounds__(256) void gemm_fused(
    const float* __restrict__ A, const float* __restrict__ Wt,
    const float* __restrict__ bias, const float* __restrict__ resid,
    float* __restrict__ C, int M, int N, int K, int relu)
{
    __shared__ float As[16][132];   // 128+4 pad: 16B-aligned rows, 2-way banks (free)
    __shared__ float Bs[16][68];    // 64+4 pad
    int tid = threadIdx.x;
    int bm = blockIdx.y * 128, bn = blockIdx.x * 64;
    int tx = tid & 15, ty = tid >> 4;    // 16 x 16 thread grid
    float acc[8][4] = {};
    int lk4 = tid & 3;      // float4 index along K
    int lr  = tid >> 2;     // row 0..63

    for (int k0 = 0; k0 < K; k0 += 16) {
        #pragma unroll
        for (int i = 0; i < 2; ++i) {
            int mrow = lr + i * 64;
            float4 av = *(const float4*)(A + (size_t)(bm + mrow) * K + k0 + lk4 * 4);
            As[lk4*4+0][mrow] = av.x; As[lk4*4+1][mrow] = av.y;
            As[lk4*4+2][mrow] = av.z; As[lk4*4+3][mrow] = av.w;
        }
        {
            float4 bv = *(const float4*)(Wt + (size_t)(bn + lr) * K + k0 + lk4 * 4);
            Bs[lk4*4+0][lr] = bv.x; Bs[lk4*4+1][lr] = bv.y;
            Bs[lk4*4+2][lr] = bv.z; Bs[lk4*4+3][lr] = bv.w;
        }
        __syncthreads();
        #pragma unroll
        for (int kk = 0; kk < 16; ++kk) {
            float4 a0 = *(const float4*)&As[kk][ty * 8];
            float4 a1 = *(const float4*)&As[kk][ty * 8 + 4];
            float4 b0 = *(const float4*)&Bs[kk][tx * 4];
            float a[8] = {a0.x,a0.y,a0.z,a0.w,a1.x,a1.y,a1.z,a1.w};
            float bbv[4] = {b0.x,b0.y,b0.z,b0.w};
            #pragma unroll
            for (int i = 0; i < 8; ++i)
                #pragma unroll
                for (int j = 0; j < 4; ++j)
                    acc[i][j] += a[i] * bbv[j];
        }
        __syncthreads();
    }
    float4 bv = *(const float4*)(bias + bn + tx * 4);
    #pragma unroll
    for (int i = 0; i < 8; ++i) {
        int mrow = bm + ty * 8 + i;
        float4 v = make_float4(acc[i][0] + bv.x, acc[i][1] + bv.y,
                               acc[i][2] + bv.z, acc[i][3] + bv.w);
        if (relu) { v.x = fmaxf(v.x, 0.f); v.y = fmaxf(v.y, 0.f);
                    v.z = fmaxf(v.z, 0.f); v.w = fmaxf(v.w, 0.f); }
        if (resid) {
            float4 r = *(const float4*)(resid + (size_t)mrow * N + bn + tx * 4);
            v.x += r.x; v.y += r.y; v.z += r.z; v.w += r.w;
        }
        *(float4*)(C + (size_t)mrow * N + bn + tx * 4) = v;
    }
}

// ---------------------------------------------------------------------------
// Flash-style attention, one block per (b, head), one query row per lane
// (512 threads). K/V tiles of 128 keys staged in LDS (32 KB). Online softmax.
// Mask (USE_MASK): attend only OUTSIDE the |dh|<=3, |dw|<=5 window (per ref).
template<int USE_MASK>
__global__ __launch_bounds__(512) void attn_kernel(const float* __restrict__ qkv,
                                                   float* __restrict__ att) {
    int b = blockIdx.x / NHd, head = blockIdx.x % NHd;
    int q_row = threadIdx.x;       // 0..511
    __shared__ float Kt[128][32];
    __shared__ float Vt[128][32];
    const float scale = 0.17677669529663687f;  // 1/sqrt(32)
    const float* base = qkv + (size_t)b * Ssz * (3 * Ed);

    float q[32];
    {
        const float4* qp = (const float4*)(base + (size_t)q_row * (3*Ed) + head * HDd);
        #pragma unroll
        for (int j = 0; j < 8; ++j) {
            float4 t4 = qp[j];
            q[4*j] = t4.x; q[4*j+1] = t4.y; q[4*j+2] = t4.z; q[4*j+3] = t4.w;
        }
    }
    float out[32];
    #pragma unroll
    for (int d = 0; d < 32; ++d) out[d] = 0.f;
    float m = -INFINITY, l = 0.f;
    int qh = q_row >> 6, qw = q_row & 63;

    for (int k0 = 0; k0 < Ssz; k0 += 128) {
        const float* kg = base + (size_t)k0 * (3*Ed) + Ed + head * HDd;
        const float* vg = kg + Ed;
        #pragma unroll
        for (int i = 0; i < 2; ++i) {
            int e = threadIdx.x + i * 512;          // float4 index, 1024 total
            int row = e >> 3, dv = e & 7;
            ((float4*)Kt)[e] = *(const float4*)(kg + (size_t)row * (3*Ed) + dv * 4);
            ((float4*)Vt)[e] = *(const float4*)(vg + (size_t)row * (3*Ed) + dv * 4);
        }
        __syncthreads();
        for (int k = 0; k < 128; ++k) {
            int kk = k0 + k;
            if (USE_MASK) {
                int dh = (kk >> 6) - qh; dh = dh < 0 ? -dh : dh;
                int dw = (kk & 63) - qw; dw = dw < 0 ? -dw : dw;
                if (dh <= 3 && dw <= 5) continue;    // inside window => -inf => p=0
            }
            float s = 0.f;
            const float4* kr = (const float4*)&Kt[k][0];
            #pragma unroll
            for (int j = 0; j < 8; ++j) {
                float4 k4 = kr[j];
                s += q[4*j]*k4.x + q[4*j+1]*k4.y + q[4*j+2]*k4.z + q[4*j+3]*k4.w;
            }
            s *= scale;
            if (s > m) {                 // rescale only on new max (alpha==1 otherwise)
                float alpha = __expf(m - s);
                l *= alpha;
                #pragma unroll
                for (int d = 0; d < 32; ++d) out[d] *= alpha;
                m = s;
            }
            float p = __expf(s - m);
            l += p;
            const float4* vr = (const float4*)&Vt[k][0];
            #pragma unroll
            for (int j = 0; j < 8; ++j) {
                float4 v4 = vr[j];
                out[4*j]   += p * v4.x; out[4*j+1] += p * v4.y;
                out[4*j+2] += p * v4.z; out[4*j+3] += p * v4.w;
            }
        }
        __syncthreads();
    }
    float inv = 1.f / l;
    float* op = att + ((size_t)b * Ssz + q_row) * Ed + head * HDd;
    #pragma unroll
    for (int j = 0; j < 8; ++j) {
        ((float4*)op)[j] = make_float4(out[4*j]*inv, out[4*j+1]*inv,
                                       out[4*j+2]*inv, out[4*j+3]*inv);
    }
}

// ---------------------------------------------------------------------------
// conv_w [CO,E,3,1] -> cwT [kh][co][c] for contiguous float4 reads in conv
__global__ __launch_bounds__(256) void transpose_cw(const float* __restrict__ cw,
                                                    float* __restrict__ cwT) {
    int t = blockIdx.x * 256 + threadIdx.x;      // 147456 total
    if (t >= 3 * COd * Ed) return;
    int kh = t / (COd * Ed);
    int r  = t % (COd * Ed);
    int co = r / Ed, c = r % Ed;
    cwT[t] = cw[((size_t)co * Ed + c) * 3 + kh];
}

// ---------------------------------------------------------------------------
// Merging conv (3,1)/(2,1)/pad(1,0) + channel LayerNorm over CO=256.
// One block per (b, ho, w); thread = output channel.
__global__ __launch_bounds__(256) void conv_ln(const float* __restrict__ X,
                                               const float* __restrict__ cwT,
                                               const float* __restrict__ cb,
                                               const float* __restrict__ g,
                                               const float* __restrict__ beta,
                                               float* __restrict__ out) {
    int w = blockIdx.x, ho = blockIdx.y, b = blockIdx.z;
    int co = threadIdx.x;
    __shared__ float xin[3][192];
    __shared__ float red[4];

    for (int e = threadIdx.x; e < 3 * Ed; e += 256) {
        int kh = e / Ed, c = e % Ed;
        int h_in = 2 * ho + kh - 1;
        float v = 0.f;
        if (h_in >= 0 && h_in < Himg)
            v = X[((size_t)b * Ssz + w * Himg + h_in) * Ed + c];
        xin[kh][c] = v;
    }
    __syncthreads();

    float acc = cb[co];
    #pragma unroll
    for (int kh = 0; kh < 3; ++kh) {
        const float4* wr = (const float4*)(cwT + ((size_t)kh * COd + co) * Ed);
        const float4* xr = (const float4*)&xin[kh][0];
        #pragma unroll 4
        for (int j = 0; j < Ed / 4; ++j) {
            float4 a = wr[j], x4 = xr[j];
            acc += a.x*x4.x + a.y*x4.y + a.z*x4.z + a.w*x4.w;
        }
    }

    // block LN over 256 channels
    int wid = threadIdx.x >> 6, lane = threadIdx.x & 63;
    float s = acc;
    #pragma unroll
    for (int off = 32; off > 0; off >>= 1) s += __shfl_xor(s, off);
    if (lane == 0) red[wid] = s;
    __syncthreads();
    float mu = (red[0] + red[1] + red[2] + red[3]) * (1.f / 256.f);
    __syncthreads();
    float d = acc - mu;
    float qv = d * d;
    #pragma unroll
    for (int off = 32; off > 0; off >>= 1) qv += __shfl_xor(qv, off);
    if (lane == 0) red[wid] = qv;
    __syncthreads();
    float var = (red[0] + red[1] + red[2] + red[3]) * (1.f / 256.f);
    float rstd = rsqrtf(var + 1e-5f);
    float y = d * rstd * g[co] + beta[co];
    out[(((size_t)b * COd + co) * 4 + ho) * Wimg + w] = y;
}

// ---------------------------------------------------------------------------
extern "C" void kernel_launch(void* const* d_in, const int* in_sizes, int n_in,
                              void* d_out, int out_size, void* d_ws, size_t ws_size,
                              hipStream_t stream) {
    const float* image = (const float*)d_in[0];
    const float* in_w  = (const float*)d_in[1];
    const float* in_b  = (const float*)d_in[2];
    const float* out_w = (const float*)d_in[3];
    const float* out_b = (const float*)d_in[4];
    const float* ln1_g = (const float*)d_in[5];
    const float* ln1_b = (const float*)d_in[6];
    const float* ln2_g = (const float*)d_in[7];
    const float* ln2_b = (const float*)d_in[8];
    const float* w1    = (const float*)d_in[9];
    const float* b1    = (const float*)d_in[10];
    const float* w2    = (const float*)d_in[11];
    const float* b2    = (const float*)d_in[12];
    const float* convw = (const float*)d_in[13];
    const float* convb = (const float*)d_in[14];
    const float* mln_g = (const float*)d_in[15];
    const float* mln_b = (const float*)d_in[16];
    float* out = (float*)d_out;
    float* ws  = (float*)d_ws;

    // workspace layout (floats):
    //  X   [32768,192] @ 0
    //  XN  [32768,192] @ 6291456      (also reused for cwT after the blocks)
    //  BIG [32768,768] @ 12582912 :  QKV = BIG[..,0:576], ATT = BIG+18874368,
    //                                 H (MLP hidden) = full BIG
    float* X   = ws;
    float* XN  = ws + 6291456;
    float* BIG = ws + 12582912;
    float* QKV = BIG;
    float* ATT = BIG + 18874368;
    float* H   = BIG;
    float* cwT = XN;   // free after last mixer block

    reshape_in<<<Mrows * Ed / 256, 256, 0, stream>>>(image, X);

    for (int i = 0; i < Ld; ++i) {
        ln_kernel<<<Mrows / 4, 256, 0, stream>>>(X, XN, ln1_g + i * Ed, ln1_b + i * Ed);
        gemm_fused<<<dim3(9, Mrows / 128), 256, 0, stream>>>(
            XN, in_w + (size_t)i * 3 * Ed * Ed, in_b + i * 3 * Ed,
            nullptr, QKV, Mrows, 3 * Ed, Ed, 0);
        if (i >= 2) attn_kernel<1><<<Bn * NHd, 512, 0, stream>>>(QKV, ATT);
        else        attn_kernel<0><<<Bn * NHd, 512, 0, stream>>>(QKV, ATT);
        gemm_fused<<<dim3(3, Mrows / 128), 256, 0, stream>>>(
            ATT, out_w + (size_t)i * Ed * Ed, out_b + i * Ed,
            XN, X, Mrows, Ed, Ed, 0);
        ln_kernel<<<Mrows / 4, 256, 0, stream>>>(X, XN, ln2_g + i * Ed, ln2_b + i * Ed);
        gemm_fused<<<dim3(12, Mrows / 128), 256, 0, stream>>>(
            XN, w1 + (size_t)i * 4 * Ed * Ed, b1 + i * 4 * Ed,
            nullptr, H, Mrows, 4 * Ed, Ed, 1);
        gemm_fused<<<dim3(3, Mrows / 128), 256, 0, stream>>>(
            H, w2 + (size_t)i * 4 * Ed * Ed, b2 + i * Ed,
            XN, X, Mrows, Ed, 4 * Ed, 0);
    }

    transpose_cw<<<576, 256, 0, stream>>>(convw, cwT);
    conv_ln<<<dim3(Wimg, 4, Bn), 256, 0, stream>>>(X, cwT, convb, mln_g, mln_b, out);
}

// Round 2
// 4305.445 us; speedup vs baseline: 1.3589x; 1.3589x over previous
//
#include <hip/hip_runtime.h>
#include <hip/hip_bf16.h>
#include <math.h>

// Problem constants
#define Bn   64
#define Ssz  512     // W*H = 64*8
#define Ed   192
#define NHd  6
#define HDd  32
#define Ld   6
#define COd  256
#define Himg 8
#define Wimg 64
#define Mrows (Bn*Ssz)   // 32768

typedef unsigned int  uint;
typedef unsigned short ushort;
using short8 = __attribute__((ext_vector_type(8))) short;
using f32x4  = __attribute__((ext_vector_type(4))) float;

__device__ inline ushort f2b(float f) {          // fp32 -> bf16 RNE
    uint u = __builtin_bit_cast(uint, f);
    u = (u + 0x7FFFu + ((u >> 16) & 1u)) >> 16;
    return (ushort)u;
}
__device__ inline float b2f(uint us) {           // bf16 (low 16 of us) -> fp32
    uint v = us << 16;
    return __builtin_bit_cast(float, v);
}

// ---------------------------------------------------------------------------
// reshape: image [B, E, 8, 64] -> X [B, S=w*8+h, E]  (fp32)
__global__ __launch_bounds__(256) void reshape_in(const float* __restrict__ img,
                                                  float* __restrict__ X) {
    int t = blockIdx.x * 256 + threadIdx.x;
    int c = t % Ed;
    int s = (t / Ed) % Ssz;
    int b = t / (Ed * Ssz);
    int w = s >> 3, h = s & 7;
    X[t] = img[(((size_t)b * Ed + c) * Himg + h) * Wimg + w];
}

// ---------------------------------------------------------------------------
// generic fp32 -> bf16 array convert
__global__ __launch_bounds__(256) void f2b_arr(const float* __restrict__ in,
                                               ushort* __restrict__ out, int n) {
    int t = blockIdx.x * 256 + threadIdx.x;
    if (t < n) out[t] = f2b(in[t]);
}

// conv_w [CO,E,3,1] -> bf16 Wt layout [co][kh*192+c]   (GEMM B operand, row=co, K contiguous)
__global__ __launch_bounds__(256) void conv_w_to_bf16(const float* __restrict__ cw,
                                                      ushort* __restrict__ out) {
    int t = blockIdx.x * 256 + threadIdx.x;      // 147456
    if (t >= COd * 576) return;
    int co = t / 576, rem = t % 576;
    int kh = rem / Ed, c = rem % Ed;
    out[t] = f2b(cw[((size_t)co * Ed + c) * 3 + kh]);
}

// ---------------------------------------------------------------------------
// LayerNorm over E=192, one wave per row; writes fp32 (residual) + bf16 (GEMM A)
__global__ __launch_bounds__(256) void ln_kernel(const float* __restrict__ in,
                                                 float* __restrict__ out,
                                                 ushort* __restrict__ outb,
                                                 const float* __restrict__ g,
                                                 const float* __restrict__ bb) {
    int row  = blockIdx.x * 4 + (threadIdx.x >> 6);
    int lane = threadIdx.x & 63;
    const float* x = in + (size_t)row * Ed;
    float v0 = x[lane], v1 = x[lane + 64], v2 = x[lane + 128];
    float s = v0 + v1 + v2;
    #pragma unroll
    for (int off = 32; off > 0; off >>= 1) s += __shfl_xor(s, off);
    float mu = s * (1.f / 192.f);
    float d0 = v0 - mu, d1 = v1 - mu, d2 = v2 - mu;
    float q = d0*d0 + d1*d1 + d2*d2;
    #pragma unroll
    for (int off = 32; off > 0; off >>= 1) q += __shfl_xor(q, off);
    float rstd = rsqrtf(q * (1.f / 192.f) + 1e-5f);
    float y0 = d0 * rstd * g[lane]       + bb[lane];
    float y1 = d1 * rstd * g[lane + 64]  + bb[lane + 64];
    float y2 = d2 * rstd * g[lane + 128] + bb[lane + 128];
    float* o = out + (size_t)row * Ed;
    o[lane] = y0; o[lane + 64] = y1; o[lane + 128] = y2;
    ushort* ob = outb + (size_t)row * Ed;
    ob[lane] = f2b(y0); ob[lane + 64] = f2b(y1); ob[lane + 128] = f2b(y2);
}

// ---------------------------------------------------------------------------
// bf16 MFMA GEMM: C[M,N] = A[M,K] @ Wt[N,K]^T + bias (+relu) (+resid) -> f32 or bf16
// BM=128 BN=64 BK=64. 128 threads = 2 waves; wave w computes rows [w*64, w*64+64).
// LDS fragment-ordered: frag f at f*64*8 ushorts, lane reads 16B at +lane*16 (conflict-free).
// mfma_f32_16x16x32_bf16: A frag row m=lane&15, k=(lane>>4)*8+j ; D: col=lane&15, row=(lane>>4)*4+r.
template<int RELU, int RESID, int OBF>
__global__ __launch_bounds__(128) void gemm_mfma(
    const ushort* __restrict__ A, const ushort* __restrict__ Wt,
    const float* __restrict__ bias, const float* __restrict__ resid,
    float* __restrict__ C, ushort* __restrict__ Cb,
    int M, int N, int K)
{
    __shared__ ushort As[8192];   // 16 frags (msub0..7 x ksub0..1) * 64 lanes * 8
    __shared__ ushort Bs[4096];   // 8 frags  (nsub0..3 x ksub0..1) * 64 lanes * 8
    const int tid  = threadIdx.x;
    const int lane = tid & 63;
    const int wave = tid >> 6;                // 0..1
    const int bm = blockIdx.y * 128;
    const int bn = blockIdx.x * 64;

    // staging address precompute
    size_t aoff[8]; int alds[8];
    #pragma unroll
    for (int i = 0; i < 8; ++i) {
        int c = tid + 128 * i;                // chunk 0..1023
        int frag = c >> 6;                    // lane_c == lane
        int m  = (frag >> 1) * 16 + (lane & 15);
        int kk = (frag & 1) * 32 + ((lane >> 4) << 3);
        aoff[i] = (size_t)(bm + m) * K + kk;
        alds[i] = c * 8;
    }
    size_t boff[4]; int blds[4];
    #pragma unroll
    for (int i = 0; i < 4; ++i) {
        int c = tid + 128 * i;                // chunk 0..511
        int frag = c >> 6;
        int n  = (frag >> 1) * 16 + (lane & 15);
        int kk = (frag & 1) * 32 + ((lane >> 4) << 3);
        boff[i] = (size_t)(bn + n) * K + kk;
        blds[i] = c * 8;
    }

    f32x4 acc[4][4];
    #pragma unroll
    for (int i = 0; i < 4; ++i)
        #pragma unroll
        for (int j = 0; j < 4; ++j) acc[i][j] = (f32x4){0.f, 0.f, 0.f, 0.f};

    for (int k0 = 0; k0 < K; k0 += 64) {
        uint4 av[8], bv[4];
        #pragma unroll
        for (int i = 0; i < 8; ++i) av[i] = *(const uint4*)(A + aoff[i] + k0);
        #pragma unroll
        for (int i = 0; i < 4; ++i) bv[i] = *(const uint4*)(Wt + boff[i] + k0);
        __syncthreads();
        #pragma unroll
        for (int i = 0; i < 8; ++i) *(uint4*)(As + alds[i]) = av[i];
        #pragma unroll
        for (int i = 0; i < 4; ++i) *(uint4*)(Bs + blds[i]) = bv[i];
        __syncthreads();

        #pragma unroll
        for (int ksub = 0; ksub < 2; ++ksub) {
            short8 af[4], bf[4];
            #pragma unroll
            for (int ms = 0; ms < 4; ++ms) {
                int f = ((wave * 4 + ms) * 2 + ksub);
                af[ms] = *(const short8*)(As + (f * 64 + lane) * 8);
            }
            #pragma unroll
            for (int ns = 0; ns < 4; ++ns) {
                int f = ns * 2 + ksub;
                bf[ns] = *(const short8*)(Bs + (f * 64 + lane) * 8);
            }
            #pragma unroll
            for (int ms = 0; ms < 4; ++ms)
                #pragma unroll
                for (int ns = 0; ns < 4; ++ns)
                    acc[ms][ns] = __builtin_amdgcn_mfma_f32_16x16x32_bf16(
                        af[ms], bf[ns], acc[ms][ns], 0, 0, 0);
        }
    }

    // epilogue
    int q = lane >> 4, colL = lane & 15;
    #pragma unroll
    for (int ms = 0; ms < 4; ++ms) {
        #pragma unroll
        for (int ns = 0; ns < 4; ++ns) {
            int row0 = bm + wave * 64 + ms * 16 + q * 4;
            int col  = bn + ns * 16 + colL;
            float bvv = bias[col];
            #pragma unroll
            for (int r = 0; r < 4; ++r) {
                float v = acc[ms][ns][r] + bvv;
                if (RELU) v = fmaxf(v, 0.f);
                if (RESID) v += resid[(size_t)(row0 + r) * N + col];
                if (OBF) Cb[(size_t)(row0 + r) * N + col] = f2b(v);
                else     C [(size_t)(row0 + r) * N + col] = v;
            }
        }
    }
}

// ---------------------------------------------------------------------------
// Flash-style attention over bf16 QKV [B,S,3E]; fp32 compute; bf16 output.
// One block per (b, head), one query row per thread (512). K/V 128-row LDS tiles.
template<int USE_MASK>
__global__ __launch_bounds__(512) void attn_kernel(const ushort* __restrict__ qkv,
                                                   ushort* __restrict__ att) {
    int b = blockIdx.x / NHd, head = blockIdx.x % NHd;
    int q_row = threadIdx.x;
    __shared__ float Kt[128][32];
    __shared__ float Vt[128][32];
    const float scale = 0.17677669529663687f;  // 1/sqrt(32)
    const ushort* base = qkv + (size_t)b * Ssz * (3 * Ed);

    float q[32];
    {
        const uint4* qp = (const uint4*)(base + (size_t)q_row * (3 * Ed) + head * HDd);
        #pragma unroll
        for (int j = 0; j < 4; ++j) {
            uint4 t4 = qp[j];
            q[8*j+0] = b2f(t4.x & 0xffff); q[8*j+1] = b2f(t4.x >> 16);
            q[8*j+2] = b2f(t4.y & 0xffff); q[8*j+3] = b2f(t4.y >> 16);
            q[8*j+4] = b2f(t4.z & 0xffff); q[8*j+5] = b2f(t4.z >> 16);
            q[8*j+6] = b2f(t4.w & 0xffff); q[8*j+7] = b2f(t4.w >> 16);
        }
    }
    float out[32];
    #pragma unroll
    for (int d = 0; d < 32; ++d) out[d] = 0.f;
    float m = -INFINITY, l = 0.f;
    int qh = q_row >> 6, qw = q_row & 63;

    for (int k0 = 0; k0 < Ssz; k0 += 128) {
        {   // stage 128 K rows + 128 V rows (bf16 -> fp32)
            int e = threadIdx.x;               // 512 chunks of 8 elems
            int row = e >> 2, dv = e & 3;
            const ushort* kg = base + (size_t)(k0 + row) * (3 * Ed) + Ed + head * HDd + dv * 8;
            uint4 kv = *(const uint4*)kg;
            uint4 vv = *(const uint4*)(kg + Ed);
            float* kd = &Kt[row][dv * 8];
            float* vd = &Vt[row][dv * 8];
            kd[0]=b2f(kv.x&0xffff); kd[1]=b2f(kv.x>>16); kd[2]=b2f(kv.y&0xffff); kd[3]=b2f(kv.y>>16);
            kd[4]=b2f(kv.z&0xffff); kd[5]=b2f(kv.z>>16); kd[6]=b2f(kv.w&0xffff); kd[7]=b2f(kv.w>>16);
            vd[0]=b2f(vv.x&0xffff); vd[1]=b2f(vv.x>>16); vd[2]=b2f(vv.y&0xffff); vd[3]=b2f(vv.y>>16);
            vd[4]=b2f(vv.z&0xffff); vd[5]=b2f(vv.z>>16); vd[6]=b2f(vv.w&0xffff); vd[7]=b2f(vv.w>>16);
        }
        __syncthreads();
        for (int k = 0; k < 128; ++k) {
            int kk = k0 + k;
            if (USE_MASK) {
                int dh = (kk >> 6) - qh; dh = dh < 0 ? -dh : dh;
                int dw = (kk & 63) - qw; dw = dw < 0 ? -dw : dw;
                if (dh <= 3 && dw <= 5) continue;    // window => -inf => p=0
            }
            float s = 0.f;
            const float4* kr = (const float4*)&Kt[k][0];
            #pragma unroll
            for (int j = 0; j < 8; ++j) {
                float4 k4 = kr[j];
                s += q[4*j]*k4.x + q[4*j+1]*k4.y + q[4*j+2]*k4.z + q[4*j+3]*k4.w;
            }
            s *= scale;
            if (s > m) {
                float alpha = __expf(m - s);
                l *= alpha;
                #pragma unroll
                for (int d = 0; d < 32; ++d) out[d] *= alpha;
                m = s;
            }
            float p = __expf(s - m);
            l += p;
            const float4* vr = (const float4*)&Vt[k][0];
            #pragma unroll
            for (int j = 0; j < 8; ++j) {
                float4 v4 = vr[j];
                out[4*j]   += p * v4.x; out[4*j+1] += p * v4.y;
                out[4*j+2] += p * v4.z; out[4*j+3] += p * v4.w;
            }
        }
        __syncthreads();
    }
    float inv = 1.f / l;
    ushort* op = att + ((size_t)b * Ssz + q_row) * Ed + head * HDd;
    #pragma unroll
    for (int j = 0; j < 4; ++j) {
        uint4 u;
        u.x = (uint)f2b(out[8*j+0]*inv) | ((uint)f2b(out[8*j+1]*inv) << 16);
        u.y = (uint)f2b(out[8*j+2]*inv) | ((uint)f2b(out[8*j+3]*inv) << 16);
        u.z = (uint)f2b(out[8*j+4]*inv) | ((uint)f2b(out[8*j+5]*inv) << 16);
        u.w = (uint)f2b(out[8*j+6]*inv) | ((uint)f2b(out[8*j+7]*inv) << 16);
        *(uint4*)(op + j * 8) = u;
    }
}

// ---------------------------------------------------------------------------
// im2col for merging conv: A2[r= (b*4+ho)*64+w][kh*192+c] = X[b, w*8+2ho+kh-1, c] (bf16)
__global__ __launch_bounds__(256) void im2col(const float* __restrict__ X,
                                              ushort* __restrict__ A2) {
    int t = blockIdx.x * 256 + threadIdx.x;      // 9437184
    int col = t % 576;
    int r   = t / 576;
    int kh = col / Ed, c = col % Ed;
    int w = r & 63, ho = (r >> 6) & 3, b = r >> 8;
    int hin = 2 * ho + kh - 1;
    float v = 0.f;
    if (hin >= 0 && hin < Himg)
        v = X[((size_t)(b * Ssz + w * Himg + hin)) * Ed + c];
    A2[t] = f2b(v);
}

// ---------------------------------------------------------------------------
// channel LN on conv output C2[r=(b*4+ho)*64+w][co=256] -> out[b,co,ho,w]
// block = (whalf, ho, b): 32 w-rows; LDS transpose for coalesced strided write.
__global__ __launch_bounds__(256) void ln_out_kernel(const float* __restrict__ C2,
                                                     const float* __restrict__ g,
                                                     const float* __restrict__ beta,
                                                     float* __restrict__ out) {
    __shared__ float lds[32 * 257];
    int w0 = blockIdx.x * 32, ho = blockIdx.y, b = blockIdx.z;
    int tid = threadIdx.x;
    size_t rbase = ((size_t)b * 4 + ho) * 64 + w0;

    for (int i = 0; i < 32; ++i)
        lds[i * 257 + tid] = C2[(rbase + i) * COd + tid];
    __syncthreads();

    int wv = tid >> 6, lane = tid & 63;
    for (int rr = 0; rr < 8; ++rr) {
        int i = wv * 8 + rr;
        float v0 = lds[i*257 + lane], v1 = lds[i*257 + lane + 64];
        float v2 = lds[i*257 + lane + 128], v3 = lds[i*257 + lane + 192];
        float s = v0 + v1 + v2 + v3;
        #pragma unroll
        for (int off = 32; off > 0; off >>= 1) s += __shfl_xor(s, off);
        float mu = s * (1.f / 256.f);
        float d0 = v0-mu, d1 = v1-mu, d2 = v2-mu, d3 = v3-mu;
        float qv = d0*d0 + d1*d1 + d2*d2 + d3*d3;
        #pragma unroll
        for (int off = 32; off > 0; off >>= 1) qv += __shfl_xor(qv, off);
        float rstd = rsqrtf(qv * (1.f / 256.f) + 1e-5f);
        lds[i*257 + lane]       = d0 * rstd * g[lane]       + beta[lane];
        lds[i*257 + lane + 64]  = d1 * rstd * g[lane + 64]  + beta[lane + 64];
        lds[i*257 + lane + 128] = d2 * rstd * g[lane + 128] + beta[lane + 128];
        lds[i*257 + lane + 192] = d3 * rstd * g[lane + 192] + beta[lane + 192];
    }
    __syncthreads();

    int w = tid & 31, half = tid >> 5;           // half 0..7
    for (int j = 0; j < 32; ++j) {
        int co = half + j * 8;
        out[(((size_t)b * COd + co) * 4 + ho) * Wimg + w0 + w] = lds[w * 257 + co];
    }
}

// ---------------------------------------------------------------------------
extern "C" void kernel_launch(void* const* d_in, const int* in_sizes, int n_in,
                              void* d_out, int out_size, void* d_ws, size_t ws_size,
                              hipStream_t stream) {
    const float* image = (const float*)d_in[0];
    const float* in_w  = (const float*)d_in[1];
    const float* in_b  = (const float*)d_in[2];
    const float* out_w = (const float*)d_in[3];
    const float* out_b = (const float*)d_in[4];
    const float* ln1_g = (const float*)d_in[5];
    const float* ln1_b = (const float*)d_in[6];
    const float* ln2_g = (const float*)d_in[7];
    const float* ln2_b = (const float*)d_in[8];
    const float* w1    = (const float*)d_in[9];
    const float* b1    = (const float*)d_in[10];
    const float* w2    = (const float*)d_in[11];
    const float* b2    = (const float*)d_in[12];
    const float* convw = (const float*)d_in[13];
    const float* convb = (const float*)d_in[14];
    const float* mln_g = (const float*)d_in[15];
    const float* mln_b = (const float*)d_in[16];
    float* out = (float*)d_out;
    float* ws  = (float*)d_ws;

    // ws layout (float units):
    //  X    [0,        6291456)
    //  XN   [6291456, 12582912)
    //  BIG  [12582912, 28311552): QKVb(bf16 18874368 el = 9437184 f) | later Hb(bf16 25165824 el)
    //                             A2b(bf16)@0 + C2(f32)@4718592 ; XNb(bf16)@+12582912f
    //  ATTb [28311552, 31457280) as bf16 (6291456 el)
    //  Wb   [31457280, 32858112) as bf16 (2801664 el)
    float* X    = ws;
    float* XN   = ws + 6291456;
    float* BIG  = ws + 12582912;
    ushort* QKVb = (ushort*)BIG;
    ushort* Hb   = (ushort*)BIG;
    ushort* A2b  = (ushort*)BIG;
    float*  C2   = BIG + 4718592;
    ushort* XNb  = (ushort*)(BIG + 12582912);
    ushort* ATTb = (ushort*)(ws + 28311552);
    ushort* Wb   = (ushort*)(ws + 31457280);

    ushort* in_wb  = Wb;                    // 663552
    ushort* out_wb = Wb + 663552;           // 221184
    ushort* w1b    = Wb + 884736;           // 884736
    ushort* w2b    = Wb + 1769472;          // 884736
    ushort* cwb    = Wb + 2654208;          // 147456

    reshape_in<<<Mrows * Ed / 256, 256, 0, stream>>>(image, X);
    f2b_arr<<<(663552 + 255) / 256, 256, 0, stream>>>(in_w,  in_wb,  663552);
    f2b_arr<<<(221184 + 255) / 256, 256, 0, stream>>>(out_w, out_wb, 221184);
    f2b_arr<<<(884736 + 255) / 256, 256, 0, stream>>>(w1,    w1b,    884736);
    f2b_arr<<<(884736 + 255) / 256, 256, 0, stream>>>(w2,    w2b,    884736);
    conv_w_to_bf16<<<(147456 + 255) / 256, 256, 0, stream>>>(convw, cwb);

    for (int i = 0; i < Ld; ++i) {
        ln_kernel<<<Mrows / 4, 256, 0, stream>>>(X, XN, XNb, ln1_g + i*Ed, ln1_b + i*Ed);
        gemm_mfma<0,0,1><<<dim3(9, Mrows/128), 128, 0, stream>>>(
            XNb, in_wb + (size_t)i * 3*Ed*Ed, in_b + i * 3*Ed,
            nullptr, nullptr, QKVb, Mrows, 3*Ed, Ed);
        if (i >= 2) attn_kernel<1><<<Bn * NHd, 512, 0, stream>>>(QKVb, ATTb);
        else        attn_kernel<0><<<Bn * NHd, 512, 0, stream>>>(QKVb, ATTb);
        gemm_mfma<0,1,0><<<dim3(3, Mrows/128), 128, 0, stream>>>(
            ATTb, out_wb + (size_t)i * Ed*Ed, out_b + i*Ed,
            XN, X, nullptr, Mrows, Ed, Ed);
        ln_kernel<<<Mrows / 4, 256, 0, stream>>>(X, XN, XNb, ln2_g + i*Ed, ln2_b + i*Ed);
        gemm_mfma<1,0,1><<<dim3(12, Mrows/128), 128, 0, stream>>>(
            XNb, w1b + (size_t)i * 4*Ed*Ed, b1 + i * 4*Ed,
            nullptr, nullptr, Hb, Mrows, 4*Ed, Ed);
        gemm_mfma<0,1,0><<<dim3(3, Mrows/128), 128, 0, stream>>>(
            Hb, w2b + (size_t)i * 4*Ed*Ed, b2 + i*Ed,
            XN, X, nullptr, Mrows, Ed, 4*Ed);
    }

    im2col<<<9437184 / 256, 256, 0, stream>>>(X, A2b);
    gemm_mfma<0,0,0><<<dim3(4, 16384/128), 128, 0, stream>>>(
        A2b, cwb, convb, nullptr, C2, nullptr, 16384, COd, 576);
    ln_out_kernel<<<dim3(2, 4, Bn), 256, 0, stream>>>(C2, mln_g, mln_b, out);
}

// Round 3
// 2481.991 us; speedup vs baseline: 2.3573x; 1.7347x over previous
//
#include <hip/hip_runtime.h>
#include <hip/hip_bf16.h>
#include <math.h>

// Problem constants
#define Bn   64
#define Ssz  512     // W*H = 64*8
#define Ed   192
#define NHd  6
#define HDd  32
#define Ld   6
#define COd  256
#define Himg 8
#define Wimg 64
#define Mrows (Bn*Ssz)   // 32768

typedef unsigned int  uint;
typedef unsigned short ushort;
using short8 = __attribute__((ext_vector_type(8))) short;
using f32x4  = __attribute__((ext_vector_type(4))) float;

__device__ inline ushort f2b(float f) {          // fp32 -> bf16 RNE
    uint u = __builtin_bit_cast(uint, f);
    u = (u + 0x7FFFu + ((u >> 16) & 1u)) >> 16;
    return (ushort)u;
}
__device__ inline float b2f(uint us) {           // bf16 (low 16 of us) -> fp32
    uint v = us << 16;
    return __builtin_bit_cast(float, v);
}

// ---------------------------------------------------------------------------
// reshape: image [B, E, 8, 64] -> X [B, S=w*8+h, E]  (fp32)
__global__ __launch_bounds__(256) void reshape_in(const float* __restrict__ img,
                                                  float* __restrict__ X) {
    int t = blockIdx.x * 256 + threadIdx.x;
    int c = t % Ed;
    int s = (t / Ed) % Ssz;
    int b = t / (Ed * Ssz);
    int w = s >> 3, h = s & 7;
    X[t] = img[(((size_t)b * Ed + c) * Himg + h) * Wimg + w];
}

// ---------------------------------------------------------------------------
// generic fp32 -> bf16 array convert
__global__ __launch_bounds__(256) void f2b_arr(const float* __restrict__ in,
                                               ushort* __restrict__ out, int n) {
    int t = blockIdx.x * 256 + threadIdx.x;
    if (t < n) out[t] = f2b(in[t]);
}

// conv_w [CO,E,3,1] -> bf16 Wt layout [co][kh*192+c]   (GEMM B operand)
__global__ __launch_bounds__(256) void conv_w_to_bf16(const float* __restrict__ cw,
                                                      ushort* __restrict__ out) {
    int t = blockIdx.x * 256 + threadIdx.x;      // 147456
    if (t >= COd * 576) return;
    int co = t / 576, rem = t % 576;
    int kh = rem / Ed, c = rem % Ed;
    out[t] = f2b(cw[((size_t)co * Ed + c) * 3 + kh]);
}

// ---------------------------------------------------------------------------
// LayerNorm over E=192, one wave per row; writes fp32 (residual) + bf16 (GEMM A)
__global__ __launch_bounds__(256) void ln_kernel(const float* __restrict__ in,
                                                 float* __restrict__ out,
                                                 ushort* __restrict__ outb,
                                                 const float* __restrict__ g,
                                                 const float* __restrict__ bb) {
    int row  = blockIdx.x * 4 + (threadIdx.x >> 6);
    int lane = threadIdx.x & 63;
    const float* x = in + (size_t)row * Ed;
    float v0 = x[lane], v1 = x[lane + 64], v2 = x[lane + 128];
    float s = v0 + v1 + v2;
    #pragma unroll
    for (int off = 32; off > 0; off >>= 1) s += __shfl_xor(s, off);
    float mu = s * (1.f / 192.f);
    float d0 = v0 - mu, d1 = v1 - mu, d2 = v2 - mu;
    float q = d0*d0 + d1*d1 + d2*d2;
    #pragma unroll
    for (int off = 32; off > 0; off >>= 1) q += __shfl_xor(q, off);
    float rstd = rsqrtf(q * (1.f / 192.f) + 1e-5f);
    float y0 = d0 * rstd * g[lane]       + bb[lane];
    float y1 = d1 * rstd * g[lane + 64]  + bb[lane + 64];
    float y2 = d2 * rstd * g[lane + 128] + bb[lane + 128];
    float* o = out + (size_t)row * Ed;
    o[lane] = y0; o[lane + 64] = y1; o[lane + 128] = y2;
    ushort* ob = outb + (size_t)row * Ed;
    ob[lane] = f2b(y0); ob[lane + 64] = f2b(y1); ob[lane + 128] = f2b(y2);
}

// ---------------------------------------------------------------------------
// bf16 MFMA GEMM: C[M,N] = A[M,K] @ Wt[N,K]^T + bias (+relu) (+resid) -> f32 or bf16
// BM=128 BN=64 BK=64. 128 threads = 2 waves.
template<int RELU, int RESID, int OBF>
__global__ __launch_bounds__(128) void gemm_mfma(
    const ushort* __restrict__ A, const ushort* __restrict__ Wt,
    const float* __restrict__ bias, const float* __restrict__ resid,
    float* __restrict__ C, ushort* __restrict__ Cb,
    int M, int N, int K)
{
    __shared__ ushort As[8192];   // 16 frags (msub0..7 x ksub0..1) * 64 lanes * 8
    __shared__ ushort Bs[4096];   // 8 frags  (nsub0..3 x ksub0..1) * 64 lanes * 8
    const int tid  = threadIdx.x;
    const int lane = tid & 63;
    const int wave = tid >> 6;                // 0..1
    const int bm = blockIdx.y * 128;
    const int bn = blockIdx.x * 64;

    size_t aoff[8]; int alds[8];
    #pragma unroll
    for (int i = 0; i < 8; ++i) {
        int c = tid + 128 * i;
        int frag = c >> 6;
        int m  = (frag >> 1) * 16 + (lane & 15);
        int kk = (frag & 1) * 32 + ((lane >> 4) << 3);
        aoff[i] = (size_t)(bm + m) * K + kk;
        alds[i] = c * 8;
    }
    size_t boff[4]; int blds[4];
    #pragma unroll
    for (int i = 0; i < 4; ++i) {
        int c = tid + 128 * i;
        int frag = c >> 6;
        int n  = (frag >> 1) * 16 + (lane & 15);
        int kk = (frag & 1) * 32 + ((lane >> 4) << 3);
        boff[i] = (size_t)(bn + n) * K + kk;
        blds[i] = c * 8;
    }

    f32x4 acc[4][4];
    #pragma unroll
    for (int i = 0; i < 4; ++i)
        #pragma unroll
        for (int j = 0; j < 4; ++j) acc[i][j] = (f32x4){0.f, 0.f, 0.f, 0.f};

    for (int k0 = 0; k0 < K; k0 += 64) {
        uint4 av[8], bv[4];
        #pragma unroll
        for (int i = 0; i < 8; ++i) av[i] = *(const uint4*)(A + aoff[i] + k0);
        #pragma unroll
        for (int i = 0; i < 4; ++i) bv[i] = *(const uint4*)(Wt + boff[i] + k0);
        __syncthreads();
        #pragma unroll
        for (int i = 0; i < 8; ++i) *(uint4*)(As + alds[i]) = av[i];
        #pragma unroll
        for (int i = 0; i < 4; ++i) *(uint4*)(Bs + blds[i]) = bv[i];
        __syncthreads();

        #pragma unroll
        for (int ksub = 0; ksub < 2; ++ksub) {
            short8 af[4], bf[4];
            #pragma unroll
            for (int ms = 0; ms < 4; ++ms) {
                int f = ((wave * 4 + ms) * 2 + ksub);
                af[ms] = *(const short8*)(As + (f * 64 + lane) * 8);
            }
            #pragma unroll
            for (int ns = 0; ns < 4; ++ns) {
                int f = ns * 2 + ksub;
                bf[ns] = *(const short8*)(Bs + (f * 64 + lane) * 8);
            }
            #pragma unroll
            for (int ms = 0; ms < 4; ++ms)
                #pragma unroll
                for (int ns = 0; ns < 4; ++ns)
                    acc[ms][ns] = __builtin_amdgcn_mfma_f32_16x16x32_bf16(
                        af[ms], bf[ns], acc[ms][ns], 0, 0, 0);
        }
    }

    int q = lane >> 4, colL = lane & 15;
    #pragma unroll
    for (int ms = 0; ms < 4; ++ms) {
        #pragma unroll
        for (int ns = 0; ns < 4; ++ns) {
            int row0 = bm + wave * 64 + ms * 16 + q * 4;
            int col  = bn + ns * 16 + colL;
            float bvv = bias[col];
            #pragma unroll
            for (int r = 0; r < 4; ++r) {
                float v = acc[ms][ns][r] + bvv;
                if (RELU) v = fmaxf(v, 0.f);
                if (RESID) v += resid[(size_t)(row0 + r) * N + col];
                if (OBF) Cb[(size_t)(row0 + r) * N + col] = f2b(v);
                else     C [(size_t)(row0 + r) * N + col] = v;
            }
        }
    }
}

// ---------------------------------------------------------------------------
// V transpose: QKV[b][s][384 + h*32 + d] -> VT[bh][d][s]   (bf16)
__global__ __launch_bounds__(256) void vt_kernel(const ushort* __restrict__ qkv,
                                                 ushort* __restrict__ vt) {
    __shared__ ushort lds[32][36];
    int bh = blockIdx.x, s0 = blockIdx.y * 32;
    int b = bh / NHd, h = bh % NHd;
    int tid = threadIdx.x;
    int row = tid >> 3, c4 = (tid & 7) * 4;
    const ushort* src = qkv + ((size_t)b * Ssz + s0 + row) * 576 + 384 + h * 32 + c4;
    *(ushort4*)&lds[row][c4] = *(const ushort4*)src;
    __syncthreads();
    int dr = tid >> 3, s4 = (tid & 7) * 4;
    ushort4 o;
    o.x = lds[s4 + 0][dr]; o.y = lds[s4 + 1][dr];
    o.z = lds[s4 + 2][dr]; o.w = lds[s4 + 3][dr];
    *(ushort4*)(vt + ((size_t)bh * 32 + dr) * 512 + s0 + s4) = o;
}

// ---------------------------------------------------------------------------
// MFMA flash attention. One wave = 16 q-rows x all 512 keys; head dim 32 = one
// mfma K. S^T = K@Q^T (C: key=(lane>>4)*4+r, q=lane&15); online softmax per q
// column via shfl_xor(16/32); P -> A-frag via 2 shfl + select; PV with VT.
template<int USE_MASK>
__global__ __launch_bounds__(256) void attn_mfma(const ushort* __restrict__ qkv,
                                                 const ushort* __restrict__ vt,
                                                 ushort* __restrict__ att) {
    const int bh = blockIdx.x;           // b*6 + h
    const int b = bh / NHd, h = bh % NHd;
    const int wave = threadIdx.x >> 6, lane = threadIdx.x & 63;
    const int q0 = blockIdx.y * 64 + wave * 16;
    const int g = lane >> 4, ql = lane & 15;
    const int sq = q0 + ql;
    const int qh = sq >> 6, qw = sq & 63;
    const float scale = 0.17677669529663687f;   // 1/sqrt(32)

    const ushort* qkbase = qkv + (size_t)b * Ssz * 576;
    short8 qf = *(const short8*)(qkbase + (size_t)sq * 576 + h * 32 + g * 8);
    const ushort* kbase = qkbase + 192 + h * 32;
    const ushort* vbase = vt + (size_t)bh * 32 * 512;

    f32x4 o0 = {0.f,0.f,0.f,0.f}, o1 = {0.f,0.f,0.f,0.f};
    float m = -INFINITY, l = 0.f;

    for (int kt = 0; kt < 16; ++kt) {
        int kb = kt * 32;
        short8 kf0 = *(const short8*)(kbase + (size_t)(kb + ql) * 576 + g * 8);
        short8 kf1 = *(const short8*)(kbase + (size_t)(kb + 16 + ql) * 576 + g * 8);
        f32x4 z = {0.f,0.f,0.f,0.f};
        f32x4 st0 = __builtin_amdgcn_mfma_f32_16x16x32_bf16(kf0, qf, z, 0, 0, 0);
        f32x4 st1 = __builtin_amdgcn_mfma_f32_16x16x32_bf16(kf1, qf, z, 0, 0, 0);
        float s[8];
        #pragma unroll
        for (int r = 0; r < 4; ++r) { s[r] = st0[r] * scale; s[4 + r] = st1[r] * scale; }
        if (USE_MASK) {
            int kh = kb >> 6;                 // no 64-boundary wrap within chunk
            int kwb = kb & 63;
            int dh = kh - qh; dh = dh < 0 ? -dh : dh;
            bool dh_ok = (dh <= 3);
            #pragma unroll
            for (int t = 0; t < 2; ++t)
                #pragma unroll
                for (int r = 0; r < 4; ++r) {
                    int kw = kwb + t * 16 + 4 * g + r;
                    int dw = kw - qw; dw = dw < 0 ? -dw : dw;
                    if (dh_ok && dw <= 5) s[t * 4 + r] = -INFINITY;
                }
        }
        float tm = s[0];
        #pragma unroll
        for (int i = 1; i < 8; ++i) tm = fmaxf(tm, s[i]);
        tm = fmaxf(tm, __shfl_xor(tm, 16));
        tm = fmaxf(tm, __shfl_xor(tm, 32));
        float mn = fmaxf(m, tm);
        float alpha = __expf(m - mn);        // first iter: exp(-inf)=0
        float p[8], ts = 0.f;
        #pragma unroll
        for (int i = 0; i < 8; ++i) { p[i] = __expf(s[i] - mn); ts += p[i]; }
        ts += __shfl_xor(ts, 16);
        ts += __shfl_xor(ts, 32);
        l = l * alpha + ts;
        m = mn;
        #pragma unroll
        for (int r = 0; r < 4; ++r) {
            float a = __shfl(alpha, 4 * g + r);
            o0[r] *= a; o1[r] *= a;
        }
        // P (S^T C-layout) -> PV A-fragment: A[q=ql][key=g*8+j]
        short8 paf;
        #pragma unroll
        for (int j = 0; j < 8; ++j) {
            int srcl = ((g & 1) * 2 + (j >> 2)) * 16 + ql;
            float v0 = __shfl(p[j & 3], srcl);
            float v1 = __shfl(p[4 + (j & 3)], srcl);
            paf[j] = (short)f2b(g >= 2 ? v1 : v0);
        }
        short8 vf0 = *(const short8*)(vbase + ((size_t)ql) * 512 + kb + g * 8);
        short8 vf1 = *(const short8*)(vbase + ((size_t)(16 + ql)) * 512 + kb + g * 8);
        o0 = __builtin_amdgcn_mfma_f32_16x16x32_bf16(paf, vf0, o0, 0, 0, 0);
        o1 = __builtin_amdgcn_mfma_f32_16x16x32_bf16(paf, vf1, o1, 0, 0, 0);
    }
    float inv = 1.f / l;
    ushort* op = att + (size_t)b * Ssz * Ed + h * 32;
    #pragma unroll
    for (int r = 0; r < 4; ++r) {
        float iv = __shfl(inv, 4 * g + r);
        int row = q0 + 4 * g + r;
        op[(size_t)row * Ed + ql]      = f2b(o0[r] * iv);
        op[(size_t)row * Ed + 16 + ql] = f2b(o1[r] * iv);
    }
}

// ---------------------------------------------------------------------------
// im2col for merging conv: A2[r=(b*4+ho)*64+w][kh*192+c] = X[b, w*8+2ho+kh-1, c]
__global__ __launch_bounds__(256) void im2col(const float* __restrict__ X,
                                              ushort* __restrict__ A2) {
    int t = blockIdx.x * 256 + threadIdx.x;      // 9437184
    int col = t % 576;
    int r   = t / 576;
    int kh = col / Ed, c = col % Ed;
    int w = r & 63, ho = (r >> 6) & 3, b = r >> 8;
    int hin = 2 * ho + kh - 1;
    float v = 0.f;
    if (hin >= 0 && hin < Himg)
        v = X[((size_t)(b * Ssz + w * Himg + hin)) * Ed + c];
    A2[t] = f2b(v);
}

// ---------------------------------------------------------------------------
// channel LN on conv output C2[r=(b*4+ho)*64+w][co=256] -> out[b,co,ho,w]
__global__ __launch_bounds__(256) void ln_out_kernel(const float* __restrict__ C2,
                                                     const float* __restrict__ g,
                                                     const float* __restrict__ beta,
                                                     float* __restrict__ out) {
    __shared__ float lds[32 * 257];
    int w0 = blockIdx.x * 32, ho = blockIdx.y, b = blockIdx.z;
    int tid = threadIdx.x;
    size_t rbase = ((size_t)b * 4 + ho) * 64 + w0;

    for (int i = 0; i < 32; ++i)
        lds[i * 257 + tid] = C2[(rbase + i) * COd + tid];
    __syncthreads();

    int wv = tid >> 6, lane = tid & 63;
    for (int rr = 0; rr < 8; ++rr) {
        int i = wv * 8 + rr;
        float v0 = lds[i*257 + lane], v1 = lds[i*257 + lane + 64];
        float v2 = lds[i*257 + lane + 128], v3 = lds[i*257 + lane + 192];
        float s = v0 + v1 + v2 + v3;
        #pragma unroll
        for (int off = 32; off > 0; off >>= 1) s += __shfl_xor(s, off);
        float mu = s * (1.f / 256.f);
        float d0 = v0-mu, d1 = v1-mu, d2 = v2-mu, d3 = v3-mu;
        float qv = d0*d0 + d1*d1 + d2*d2 + d3*d3;
        #pragma unroll
        for (int off = 32; off > 0; off >>= 1) qv += __shfl_xor(qv, off);
        float rstd = rsqrtf(qv * (1.f / 256.f) + 1e-5f);
        lds[i*257 + lane]       = d0 * rstd * g[lane]       + beta[lane];
        lds[i*257 + lane + 64]  = d1 * rstd * g[lane + 64]  + beta[lane + 64];
        lds[i*257 + lane + 128] = d2 * rstd * g[lane + 128] + beta[lane + 128];
        lds[i*257 + lane + 192] = d3 * rstd * g[lane + 192] + beta[lane + 192];
    }
    __syncthreads();

    int w = tid & 31, half = tid >> 5;
    for (int j = 0; j < 32; ++j) {
        int co = half + j * 8;
        out[(((size_t)b * COd + co) * 4 + ho) * Wimg + w0 + w] = lds[w * 257 + co];
    }
}

// ---------------------------------------------------------------------------
extern "C" void kernel_launch(void* const* d_in, const int* in_sizes, int n_in,
                              void* d_out, int out_size, void* d_ws, size_t ws_size,
                              hipStream_t stream) {
    const float* image = (const float*)d_in[0];
    const float* in_w  = (const float*)d_in[1];
    const float* in_b  = (const float*)d_in[2];
    const float* out_w = (const float*)d_in[3];
    const float* out_b = (const float*)d_in[4];
    const float* ln1_g = (const float*)d_in[5];
    const float* ln1_b = (const float*)d_in[6];
    const float* ln2_g = (const float*)d_in[7];
    const float* ln2_b = (const float*)d_in[8];
    const float* w1    = (const float*)d_in[9];
    const float* b1    = (const float*)d_in[10];
    const float* w2    = (const float*)d_in[11];
    const float* b2    = (const float*)d_in[12];
    const float* convw = (const float*)d_in[13];
    const float* convb = (const float*)d_in[14];
    const float* mln_g = (const float*)d_in[15];
    const float* mln_b = (const float*)d_in[16];
    float* out = (float*)d_out;
    float* ws  = (float*)d_ws;

    // ws layout (float units):
    //  X    [0, 6291456)
    //  XN   [6291456, 12582912)
    //  BIG  [12582912, 28311552):
    //       QKVb bf16 @BIG (9437184 f) | VT bf16 @+9437184 (3145728 f)
    //       Hb bf16 (12582912 f, clobbers VT after attention)
    //       A2b bf16 @BIG + C2 f32 @BIG+4718592 (conv path, end)
    //  XNb  bf16 @ BIG+12582912  [25165824, 28311552)
    //  ATTb bf16 [28311552, 31457280)
    //  Wb   bf16 [31457280, 32858112)
    float* X    = ws;
    float* XN   = ws + 6291456;
    float* BIG  = ws + 12582912;
    ushort* QKVb = (ushort*)BIG;
    ushort* VT   = (ushort*)(BIG + 9437184);
    ushort* Hb   = (ushort*)BIG;
    ushort* A2b  = (ushort*)BIG;
    float*  C2   = BIG + 4718592;
    ushort* XNb  = (ushort*)(BIG + 12582912);
    ushort* ATTb = (ushort*)(ws + 28311552);
    ushort* Wb   = (ushort*)(ws + 31457280);

    ushort* in_wb  = Wb;                    // 663552
    ushort* out_wb = Wb + 663552;           // 221184
    ushort* w1b    = Wb + 884736;           // 884736
    ushort* w2b    = Wb + 1769472;          // 884736
    ushort* cwb    = Wb + 2654208;          // 147456

    reshape_in<<<Mrows * Ed / 256, 256, 0, stream>>>(image, X);
    f2b_arr<<<(663552 + 255) / 256, 256, 0, stream>>>(in_w,  in_wb,  663552);
    f2b_arr<<<(221184 + 255) / 256, 256, 0, stream>>>(out_w, out_wb, 221184);
    f2b_arr<<<(884736 + 255) / 256, 256, 0, stream>>>(w1,    w1b,    884736);
    f2b_arr<<<(884736 + 255) / 256, 256, 0, stream>>>(w2,    w2b,    884736);
    conv_w_to_bf16<<<(147456 + 255) / 256, 256, 0, stream>>>(convw, cwb);

    for (int i = 0; i < Ld; ++i) {
        ln_kernel<<<Mrows / 4, 256, 0, stream>>>(X, XN, XNb, ln1_g + i*Ed, ln1_b + i*Ed);
        gemm_mfma<0,0,1><<<dim3(9, Mrows/128), 128, 0, stream>>>(
            XNb, in_wb + (size_t)i * 3*Ed*Ed, in_b + i * 3*Ed,
            nullptr, nullptr, QKVb, Mrows, 3*Ed, Ed);
        vt_kernel<<<dim3(Bn * NHd, 16), 256, 0, stream>>>(QKVb, VT);
        if (i >= 2) attn_mfma<1><<<dim3(Bn * NHd, 8), 256, 0, stream>>>(QKVb, VT, ATTb);
        else        attn_mfma<0><<<dim3(Bn * NHd, 8), 256, 0, stream>>>(QKVb, VT, ATTb);
        gemm_mfma<0,1,0><<<dim3(3, Mrows/128), 128, 0, stream>>>(
            ATTb, out_wb + (size_t)i * Ed*Ed, out_b + i*Ed,
            XN, X, nullptr, Mrows, Ed, Ed);
        ln_kernel<<<Mrows / 4, 256, 0, stream>>>(X, XN, XNb, ln2_g + i*Ed, ln2_b + i*Ed);
        gemm_mfma<1,0,1><<<dim3(12, Mrows/128), 128, 0, stream>>>(
            XNb, w1b + (size_t)i * 4*Ed*Ed, b1 + i * 4*Ed,
            nullptr, nullptr, Hb, Mrows, 4*Ed, Ed);
        gemm_mfma<0,1,0><<<dim3(3, Mrows/128), 128, 0, stream>>>(
            Hb, w2b + (size_t)i * 4*Ed*Ed, b2 + i*Ed,
            XN, X, nullptr, Mrows, Ed, 4*Ed);
    }

    im2col<<<9437184 / 256, 256, 0, stream>>>(X, A2b);
    gemm_mfma<0,0,0><<<dim3(4, 16384/128), 128, 0, stream>>>(
        A2b, cwb, convb, nullptr, C2, nullptr, 16384, COd, 576);
    ln_out_kernel<<<dim3(2, 4, Bn), 256, 0, stream>>>(C2, mln_g, mln_b, out);
}

// Round 4
// 1652.753 us; speedup vs baseline: 3.5400x; 1.5017x over previous
//
#include <hip/hip_runtime.h>
#include <hip/hip_bf16.h>
#include <math.h>

// Problem constants
#define Bn   64
#define Ssz  512     // W*H = 64*8
#define Ed   192
#define NHd  6
#define HDd  32
#define Ld   6
#define COd  256
#define Himg 8
#define Wimg 64
#define Mrows (Bn*Ssz)   // 32768

typedef unsigned int  uint;
typedef unsigned short ushort;
using short8 = __attribute__((ext_vector_type(8))) short;
using f32x4  = __attribute__((ext_vector_type(4))) float;

__device__ inline ushort f2b(float f) {          // fp32 -> bf16 RNE
    uint u = __builtin_bit_cast(uint, f);
    u = (u + 0x7FFFu + ((u >> 16) & 1u)) >> 16;
    return (ushort)u;
}
__device__ inline float b2f(uint us) {
    uint v = us << 16;
    return __builtin_bit_cast(float, v);
}

// async global->LDS 16B: lane i lands at lds + i*16 (wave-uniform lds base)
__device__ __forceinline__ void gload16(const ushort* g, ushort* l, int lane) {
#if __has_builtin(__builtin_amdgcn_global_load_lds)
    __builtin_amdgcn_global_load_lds(
        (const __attribute__((address_space(1))) uint*)g,
        (__attribute__((address_space(3))) uint*)l, 16, 0, 0);
#else
    *(uint4*)(l + (size_t)lane * 8) = *(const uint4*)g;
#endif
}

// ---------------------------------------------------------------------------
// reshape: image [B, E, 8, 64] -> X [B, S=w*8+h, E]  (fp32)
__global__ __launch_bounds__(256) void reshape_in(const float* __restrict__ img,
                                                  float* __restrict__ X) {
    int t = blockIdx.x * 256 + threadIdx.x;
    int c = t % Ed;
    int s = (t / Ed) % Ssz;
    int b = t / (Ed * Ssz);
    int w = s >> 3, h = s & 7;
    X[t] = img[(((size_t)b * Ed + c) * Himg + h) * Wimg + w];
}

// ---------------------------------------------------------------------------
__global__ __launch_bounds__(256) void f2b_arr(const float* __restrict__ in,
                                               ushort* __restrict__ out, int n) {
    int t = blockIdx.x * 256 + threadIdx.x;
    if (t < n) out[t] = f2b(in[t]);
}

// conv_w [CO,E,3,1] -> bf16 layout [co][kh*192+c]
__global__ __launch_bounds__(256) void conv_w_to_bf16(const float* __restrict__ cw,
                                                      ushort* __restrict__ out) {
    int t = blockIdx.x * 256 + threadIdx.x;
    if (t >= COd * 576) return;
    int co = t / 576, rem = t % 576;
    int kh = rem / Ed, c = rem % Ed;
    out[t] = f2b(cw[((size_t)co * Ed + c) * 3 + kh]);
}

// ---------------------------------------------------------------------------
// LayerNorm over E=192, one wave per row, lanes 0..47 hold float4 each.
__global__ __launch_bounds__(256) void ln_kernel(const float* __restrict__ in,
                                                 float* __restrict__ out,
                                                 ushort* __restrict__ outb,
                                                 const float* __restrict__ g,
                                                 const float* __restrict__ bb) {
    int row  = blockIdx.x * 4 + (threadIdx.x >> 6);
    int lane = threadIdx.x & 63;
    bool act = lane < 48;
    float4 v = make_float4(0.f, 0.f, 0.f, 0.f);
    if (act) v = ((const float4*)(in + (size_t)row * Ed))[lane];
    float s = v.x + v.y + v.z + v.w;
    #pragma unroll
    for (int off = 32; off > 0; off >>= 1) s += __shfl_xor(s, off);
    float mu = s * (1.f / 192.f);
    float4 d = make_float4(v.x - mu, v.y - mu, v.z - mu, v.w - mu);
    float qv = act ? (d.x*d.x + d.y*d.y + d.z*d.z + d.w*d.w) : 0.f;
    #pragma unroll
    for (int off = 32; off > 0; off >>= 1) qv += __shfl_xor(qv, off);
    float rstd = rsqrtf(qv * (1.f / 192.f) + 1e-5f);
    if (act) {
        float4 gg  = ((const float4*)g)[lane];
        float4 bbv = ((const float4*)bb)[lane];
        float4 y = make_float4(d.x * rstd * gg.x + bbv.x,
                               d.y * rstd * gg.y + bbv.y,
                               d.z * rstd * gg.z + bbv.z,
                               d.w * rstd * gg.w + bbv.w);
        ((float4*)(out + (size_t)row * Ed))[lane] = y;
        ushort4 yb;
        yb.x = f2b(y.x); yb.y = f2b(y.y); yb.z = f2b(y.z); yb.w = f2b(y.w);
        *(ushort4*)(outb + (size_t)row * Ed + lane * 4) = yb;
    }
}

// ---------------------------------------------------------------------------
// bf16 MFMA GEMM: C[M,N] = A[M,K] @ Wt[N,K]^T + bias (+relu) (+resid)
// BM=128 BN=64 BK=96; 256 threads = 4 waves (2x2). Staging via global_load_lds.
// LDS fragment-ordered; frag f at f*1024B, lane reads 16B at +lane*16.
template<int RELU, int RESID, int OBF>
__global__ __launch_bounds__(256) void gemm_mfma(
    const ushort* __restrict__ A, const ushort* __restrict__ Wt,
    const float* __restrict__ bias, const float* __restrict__ resid,
    float* __restrict__ C, ushort* __restrict__ Cb,
    int M, int N, int K)
{
    __shared__ __align__(16) ushort As[12288];   // 24 frags (8 msub x 3 ksub) * 1KB
    __shared__ __align__(16) ushort Bs[6144];    // 12 frags (4 nsub x 3 ksub) * 1KB
    const int tid  = threadIdx.x;
    const int lane = tid & 63;
    const int wave = tid >> 6;
    const int wr = wave >> 1, wc = wave & 1;
    const int bm = blockIdx.y * 128;
    const int bn = blockIdx.x * 64;

    const ushort* Ag[6]; ushort* Al[6];
    #pragma unroll
    for (int i = 0; i < 6; ++i) {
        int fa = 4 * i + wave;                 // 0..23
        int msub = fa / 3, ksub = fa % 3;
        int m = msub * 16 + (lane & 15);
        int k = ksub * 32 + ((lane >> 4) << 3);
        Ag[i] = A + (size_t)(bm + m) * K + k;
        Al[i] = As + fa * 512;                 // wave-uniform
    }
    const ushort* Bg[3]; ushort* Bl[3];
    #pragma unroll
    for (int i = 0; i < 3; ++i) {
        int fb = 4 * i + wave;                 // 0..11
        int nsub = fb / 3, ksub = fb % 3;
        int n = nsub * 16 + (lane & 15);
        int k = ksub * 32 + ((lane >> 4) << 3);
        Bg[i] = Wt + (size_t)(bn + n) * K + k;
        Bl[i] = Bs + fb * 512;
    }

    f32x4 acc[4][2];
    #pragma unroll
    for (int i = 0; i < 4; ++i)
        #pragma unroll
        for (int j = 0; j < 2; ++j) acc[i][j] = (f32x4){0.f, 0.f, 0.f, 0.f};

    for (int k0 = 0; k0 < K; k0 += 96) {
        #pragma unroll
        for (int i = 0; i < 6; ++i) gload16(Ag[i] + k0, Al[i], lane);
        #pragma unroll
        for (int i = 0; i < 3; ++i) gload16(Bg[i] + k0, Bl[i], lane);
        __syncthreads();                        // waits vmcnt(0) -> LDS valid
        #pragma unroll
        for (int ksub = 0; ksub < 3; ++ksub) {
            short8 af[4], bf[2];
            #pragma unroll
            for (int ms = 0; ms < 4; ++ms)
                af[ms] = *(const short8*)(As + (((wr*4+ms)*3 + ksub) * 64 + lane) * 8);
            #pragma unroll
            for (int ns = 0; ns < 2; ++ns)
                bf[ns] = *(const short8*)(Bs + (((wc*2+ns)*3 + ksub) * 64 + lane) * 8);
            #pragma unroll
            for (int ms = 0; ms < 4; ++ms)
                #pragma unroll
                for (int ns = 0; ns < 2; ++ns)
                    acc[ms][ns] = __builtin_amdgcn_mfma_f32_16x16x32_bf16(
                        af[ms], bf[ns], acc[ms][ns], 0, 0, 0);
        }
        __syncthreads();
    }

    int q = lane >> 4, colL = lane & 15;
    #pragma unroll
    for (int ms = 0; ms < 4; ++ms) {
        #pragma unroll
        for (int ns = 0; ns < 2; ++ns) {
            int row0 = bm + (wr*4 + ms) * 16 + q * 4;
            int col  = bn + (wc*2 + ns) * 16 + colL;
            float bvv = bias[col];
            #pragma unroll
            for (int r = 0; r < 4; ++r) {
                float v = acc[ms][ns][r] + bvv;
                if (RELU) v = fmaxf(v, 0.f);
                if (RESID) v += resid[(size_t)(row0 + r) * N + col];
                if (OBF) Cb[(size_t)(row0 + r) * N + col] = f2b(v);
                else     C [(size_t)(row0 + r) * N + col] = v;
            }
        }
    }
}

// ---------------------------------------------------------------------------
// V transpose: QKV[b][s][384 + h*32 + d] -> VT[bh][d][s]   (bf16)
__global__ __launch_bounds__(256) void vt_kernel(const ushort* __restrict__ qkv,
                                                 ushort* __restrict__ vt) {
    __shared__ ushort lds[32][36];
    int bh = blockIdx.x, s0 = blockIdx.y * 32;
    int b = bh / NHd, h = bh % NHd;
    int tid = threadIdx.x;
    int row = tid >> 3, c4 = (tid & 7) * 4;
    const ushort* src = qkv + ((size_t)b * Ssz + s0 + row) * 576 + 384 + h * 32 + c4;
    *(ushort4*)&lds[row][c4] = *(const ushort4*)src;
    __syncthreads();
    int dr = tid >> 3, s4 = (tid & 7) * 4;
    ushort4 o;
    o.x = lds[s4 + 0][dr]; o.y = lds[s4 + 1][dr];
    o.z = lds[s4 + 2][dr]; o.w = lds[s4 + 3][dr];
    *(ushort4*)(vt + ((size_t)bh * 32 + dr) * 512 + s0 + s4) = o;
}

// ---------------------------------------------------------------------------
// MFMA attention, unshifted softmax (scores provably < 80): p=exp(s*scale),
// single end normalization. One wave = 16 q x 512 keys.
// S^T = K@Q^T (C: key=4g+r, q=ql); P -> A-frag via wave-private LDS tile.
template<int USE_MASK>
__global__ __launch_bounds__(256) void attn_mfma(const ushort* __restrict__ qkv,
                                                 const ushort* __restrict__ vt,
                                                 ushort* __restrict__ att) {
    __shared__ __align__(16) ushort Pw[4][16][40];   // stride 40: ~conflict-free
    const int bh = blockIdx.x;
    const int b = bh / NHd, h = bh % NHd;
    const int wave = threadIdx.x >> 6, lane = threadIdx.x & 63;
    const int g = lane >> 4, ql = lane & 15;
    const int q0 = blockIdx.y * 64 + wave * 16;
    const int sq = q0 + ql;
    const int qh = blockIdx.y;            // sq>>6 (block 64-aligned)
    const int qw = wave * 16 + ql;        // sq&63
    const float scale = 0.17677669529663687f;   // 1/sqrt(32)

    const ushort* qkbase = qkv + (size_t)b * Ssz * 576;
    short8 qf = *(const short8*)(qkbase + (size_t)sq * 576 + h * 32 + g * 8);
    const ushort* kbase = qkbase + 192 + h * 32;
    const ushort* vbase = vt + (size_t)bh * 32 * 512;

    // per-lane window masks for the two kw-base cases (multiplicative)
    float pm0[8], pm1[8];
    if (USE_MASK) {
        #pragma unroll
        for (int i = 0; i < 8; ++i) {
            int keyl = (i >> 2) * 16 + 4 * g + (i & 3);
            int dw0 = keyl - qw;      dw0 = dw0 < 0 ? -dw0 : dw0;
            int dw1 = keyl + 32 - qw; dw1 = dw1 < 0 ? -dw1 : dw1;
            pm0[i] = (dw0 <= 5) ? 0.f : 1.f;
            pm1[i] = (dw1 <= 5) ? 0.f : 1.f;
        }
    }

    f32x4 o0 = {0.f,0.f,0.f,0.f}, o1 = {0.f,0.f,0.f,0.f};
    float lacc = 0.f;
    const f32x4 z = {0.f,0.f,0.f,0.f};

    for (int kt = 0; kt < 16; ++kt) {
        int kb = kt * 32;
        short8 kf0 = *(const short8*)(kbase + (size_t)(kb + ql) * 576 + g * 8);
        short8 kf1 = *(const short8*)(kbase + (size_t)(kb + 16 + ql) * 576 + g * 8);
        f32x4 st0 = __builtin_amdgcn_mfma_f32_16x16x32_bf16(kf0, qf, z, 0, 0, 0);
        f32x4 st1 = __builtin_amdgcn_mfma_f32_16x16x32_bf16(kf1, qf, z, 0, 0, 0);
        float p[8];
        #pragma unroll
        for (int r = 0; r < 4; ++r) {
            p[r]     = __expf(st0[r] * scale);
            p[4 + r] = __expf(st1[r] * scale);
        }
        if (USE_MASK) {
            int dh = (kt >> 1) - qh; dh = dh < 0 ? -dh : dh;
            if (dh <= 3) {                       // wave-uniform branch
                const float* pm = (kt & 1) ? pm1 : pm0;
                #pragma unroll
                for (int i = 0; i < 8; ++i) p[i] *= pm[i];
            }
        }
        #pragma unroll
        for (int i = 0; i < 8; ++i) lacc += p[i];
        // pack bf16 (round-half-up) and transpose via wave-private LDS
        uint u[8];
        #pragma unroll
        for (int i = 0; i < 8; ++i) u[i] = __builtin_bit_cast(uint, p[i]) + 0x8000u;
        uint2 w0, w1;
        w0.x = __builtin_amdgcn_perm(u[1], u[0], 0x07060302u);
        w0.y = __builtin_amdgcn_perm(u[3], u[2], 0x07060302u);
        w1.x = __builtin_amdgcn_perm(u[5], u[4], 0x07060302u);
        w1.y = __builtin_amdgcn_perm(u[7], u[6], 0x07060302u);
        *(uint2*)&Pw[wave][ql][4 * g]      = w0;   // keys 4g..4g+3
        *(uint2*)&Pw[wave][ql][16 + 4 * g] = w1;   // keys 16+4g..16+4g+3
        __asm__ __volatile__("s_waitcnt lgkmcnt(0)" ::: "memory");
        short8 paf = *(const short8*)&Pw[wave][ql][8 * g];    // A[q=ql][k=8g..8g+7]
        short8 vf0 = *(const short8*)(vbase + (size_t)ql * 512 + kb + 8 * g);
        short8 vf1 = *(const short8*)(vbase + (size_t)(16 + ql) * 512 + kb + 8 * g);
        o0 = __builtin_amdgcn_mfma_f32_16x16x32_bf16(paf, vf0, o0, 0, 0, 0);
        o1 = __builtin_amdgcn_mfma_f32_16x16x32_bf16(paf, vf1, o1, 0, 0, 0);
    }
    lacc += __shfl_xor(lacc, 16);
    lacc += __shfl_xor(lacc, 32);
    float inv = 1.f / lacc;
    ushort* op = att + (size_t)b * Ssz * Ed + h * 32;
    #pragma unroll
    for (int r = 0; r < 4; ++r) {
        float iv = __shfl(inv, 4 * g + r);
        int row = q0 + 4 * g + r;
        op[(size_t)row * Ed + ql]      = f2b(o0[r] * iv);
        op[(size_t)row * Ed + 16 + ql] = f2b(o1[r] * iv);
    }
}

// ---------------------------------------------------------------------------
// im2col for merging conv: A2[r=(b*4+ho)*64+w][kh*192+c] = X[b, w*8+2ho+kh-1, c]
__global__ __launch_bounds__(256) void im2col(const float* __restrict__ X,
                                              ushort* __restrict__ A2) {
    int t = blockIdx.x * 256 + threadIdx.x;      // 9437184
    int col = t % 576;
    int r   = t / 576;
    int kh = col / Ed, c = col % Ed;
    int w = r & 63, ho = (r >> 6) & 3, b = r >> 8;
    int hin = 2 * ho + kh - 1;
    float v = 0.f;
    if (hin >= 0 && hin < Himg)
        v = X[((size_t)(b * Ssz + w * Himg + hin)) * Ed + c];
    A2[t] = f2b(v);
}

// ---------------------------------------------------------------------------
// channel LN on conv output C2[r=(b*4+ho)*64+w][co=256] -> out[b,co,ho,w]
__global__ __launch_bounds__(256) void ln_out_kernel(const float* __restrict__ C2,
                                                     const float* __restrict__ g,
                                                     const float* __restrict__ beta,
                                                     float* __restrict__ out) {
    __shared__ float lds[32 * 257];
    int w0 = blockIdx.x * 32, ho = blockIdx.y, b = blockIdx.z;
    int tid = threadIdx.x;
    size_t rbase = ((size_t)b * 4 + ho) * 64 + w0;

    for (int i = 0; i < 32; ++i)
        lds[i * 257 + tid] = C2[(rbase + i) * COd + tid];
    __syncthreads();

    int wv = tid >> 6, lane = tid & 63;
    for (int rr = 0; rr < 8; ++rr) {
        int i = wv * 8 + rr;
        float v0 = lds[i*257 + lane], v1 = lds[i*257 + lane + 64];
        float v2 = lds[i*257 + lane + 128], v3 = lds[i*257 + lane + 192];
        float s = v0 + v1 + v2 + v3;
        #pragma unroll
        for (int off = 32; off > 0; off >>= 1) s += __shfl_xor(s, off);
        float mu = s * (1.f / 256.f);
        float d0 = v0-mu, d1 = v1-mu, d2 = v2-mu, d3 = v3-mu;
        float qv = d0*d0 + d1*d1 + d2*d2 + d3*d3;
        #pragma unroll
        for (int off = 32; off > 0; off >>= 1) qv += __shfl_xor(qv, off);
        float rstd = rsqrtf(qv * (1.f / 256.f) + 1e-5f);
        lds[i*257 + lane]       = d0 * rstd * g[lane]       + beta[lane];
        lds[i*257 + lane + 64]  = d1 * rstd * g[lane + 64]  + beta[lane + 64];
        lds[i*257 + lane + 128] = d2 * rstd * g[lane + 128] + beta[lane + 128];
        lds[i*257 + lane + 192] = d3 * rstd * g[lane + 192] + beta[lane + 192];
    }
    __syncthreads();

    int w = tid & 31, half = tid >> 5;
    for (int j = 0; j < 32; ++j) {
        int co = half + j * 8;
        out[(((size_t)b * COd + co) * 4 + ho) * Wimg + w0 + w] = lds[w * 257 + co];
    }
}

// ---------------------------------------------------------------------------
extern "C" void kernel_launch(void* const* d_in, const int* in_sizes, int n_in,
                              void* d_out, int out_size, void* d_ws, size_t ws_size,
                              hipStream_t stream) {
    const float* image = (const float*)d_in[0];
    const float* in_w  = (const float*)d_in[1];
    const float* in_b  = (const float*)d_in[2];
    const float* out_w = (const float*)d_in[3];
    const float* out_b = (const float*)d_in[4];
    const float* ln1_g = (const float*)d_in[5];
    const float* ln1_b = (const float*)d_in[6];
    const float* ln2_g = (const float*)d_in[7];
    const float* ln2_b = (const float*)d_in[8];
    const float* w1    = (const float*)d_in[9];
    const float* b1    = (const float*)d_in[10];
    const float* w2    = (const float*)d_in[11];
    const float* b2    = (const float*)d_in[12];
    const float* convw = (const float*)d_in[13];
    const float* convb = (const float*)d_in[14];
    const float* mln_g = (const float*)d_in[15];
    const float* mln_b = (const float*)d_in[16];
    float* out = (float*)d_out;
    float* ws  = (float*)d_ws;

    // ws layout (float units) — same as round 3
    float* X    = ws;
    float* XN   = ws + 6291456;
    float* BIG  = ws + 12582912;
    ushort* QKVb = (ushort*)BIG;
    ushort* VT   = (ushort*)(BIG + 9437184);
    ushort* Hb   = (ushort*)BIG;
    ushort* A2b  = (ushort*)BIG;
    float*  C2   = BIG + 4718592;
    ushort* XNb  = (ushort*)(BIG + 12582912);
    ushort* ATTb = (ushort*)(ws + 28311552);
    ushort* Wb   = (ushort*)(ws + 31457280);

    ushort* in_wb  = Wb;                    // 663552
    ushort* out_wb = Wb + 663552;           // 221184
    ushort* w1b    = Wb + 884736;           // 884736
    ushort* w2b    = Wb + 1769472;          // 884736
    ushort* cwb    = Wb + 2654208;          // 147456

    reshape_in<<<Mrows * Ed / 256, 256, 0, stream>>>(image, X);
    f2b_arr<<<(663552 + 255) / 256, 256, 0, stream>>>(in_w,  in_wb,  663552);
    f2b_arr<<<(221184 + 255) / 256, 256, 0, stream>>>(out_w, out_wb, 221184);
    f2b_arr<<<(884736 + 255) / 256, 256, 0, stream>>>(w1,    w1b,    884736);
    f2b_arr<<<(884736 + 255) / 256, 256, 0, stream>>>(w2,    w2b,    884736);
    conv_w_to_bf16<<<(147456 + 255) / 256, 256, 0, stream>>>(convw, cwb);

    for (int i = 0; i < Ld; ++i) {
        ln_kernel<<<Mrows / 4, 256, 0, stream>>>(X, XN, XNb, ln1_g + i*Ed, ln1_b + i*Ed);
        gemm_mfma<0,0,1><<<dim3(9, Mrows/128), 256, 0, stream>>>(
            XNb, in_wb + (size_t)i * 3*Ed*Ed, in_b + i * 3*Ed,
            nullptr, nullptr, QKVb, Mrows, 3*Ed, Ed);
        vt_kernel<<<dim3(Bn * NHd, 16), 256, 0, stream>>>(QKVb, VT);
        if (i >= 2) attn_mfma<1><<<dim3(Bn * NHd, 8), 256, 0, stream>>>(QKVb, VT, ATTb);
        else        attn_mfma<0><<<dim3(Bn * NHd, 8), 256, 0, stream>>>(QKVb, VT, ATTb);
        gemm_mfma<0,1,0><<<dim3(3, Mrows/128), 256, 0, stream>>>(
            ATTb, out_wb + (size_t)i * Ed*Ed, out_b + i*Ed,
            XN, X, nullptr, Mrows, Ed, Ed);
        ln_kernel<<<Mrows / 4, 256, 0, stream>>>(X, XN, XNb, ln2_g + i*Ed, ln2_b + i*Ed);
        gemm_mfma<1,0,1><<<dim3(12, Mrows/128), 256, 0, stream>>>(
            XNb, w1b + (size_t)i * 4*Ed*Ed, b1 + i * 4*Ed,
            nullptr, nullptr, Hb, Mrows, 4*Ed, Ed);
        gemm_mfma<0,1,0><<<dim3(3, Mrows/128), 256, 0, stream>>>(
            Hb, w2b + (size_t)i * 4*Ed*Ed, b2 + i*Ed,
            XN, X, nullptr, Mrows, Ed, 4*Ed);
    }

    im2col<<<9437184 / 256, 256, 0, stream>>>(X, A2b);
    gemm_mfma<0,0,0><<<dim3(4, 16384/128), 256, 0, stream>>>(
        A2b, cwb, convb, nullptr, C2, nullptr, 16384, COd, 576);
    ln_out_kernel<<<dim3(2, 4, Bn), 256, 0, stream>>>(C2, mln_g, mln_b, out);
}

// Round 5
// 1592.854 us; speedup vs baseline: 3.6732x; 1.0376x over previous
//
#include <hip/hip_runtime.h>
#include <hip/hip_bf16.h>
#include <math.h>

// Problem constants
#define Bn   64
#define Ssz  512     // W*H = 64*8
#define Ed   192
#define NHd  6
#define HDd  32
#define Ld   6
#define COd  256
#define Himg 8
#define Wimg 64
#define Mrows (Bn*Ssz)   // 32768

typedef unsigned int  uint;
typedef unsigned short ushort;
using short8 = __attribute__((ext_vector_type(8))) short;
using f32x4  = __attribute__((ext_vector_type(4))) float;

#define WAIT_LGKM() __asm__ __volatile__("s_waitcnt lgkmcnt(0)" ::: "memory")

__device__ inline ushort f2b(float f) {          // fp32 -> bf16 RNE
    uint u = __builtin_bit_cast(uint, f);
    u = (u + 0x7FFFu + ((u >> 16) & 1u)) >> 16;
    return (ushort)u;
}
__device__ inline float b2f(uint us) {
    uint v = us << 16;
    return __builtin_bit_cast(float, v);
}

// async global->LDS 16B: lane i lands at lds + i*16 (wave-uniform lds base)
__device__ __forceinline__ void gload16(const ushort* g, ushort* l, int lane) {
#if __has_builtin(__builtin_amdgcn_global_load_lds)
    __builtin_amdgcn_global_load_lds(
        (const __attribute__((address_space(1))) uint*)g,
        (__attribute__((address_space(3))) uint*)l, 16, 0, 0);
#else
    *(uint4*)(l + (size_t)lane * 8) = *(const uint4*)g;
#endif
}

// ---------------------------------------------------------------------------
// reshape: image [B, E, 8, 64] -> X [B, S=w*8+h, E]  (fp32)
__global__ __launch_bounds__(256) void reshape_in(const float* __restrict__ img,
                                                  float* __restrict__ X) {
    int t = blockIdx.x * 256 + threadIdx.x;
    int c = t % Ed;
    int s = (t / Ed) % Ssz;
    int b = t / (Ed * Ssz);
    int w = s >> 3, h = s & 7;
    X[t] = img[(((size_t)b * Ed + c) * Himg + h) * Wimg + w];
}

// ---------------------------------------------------------------------------
__global__ __launch_bounds__(256) void f2b_arr(const float* __restrict__ in,
                                               ushort* __restrict__ out, int n) {
    int t = blockIdx.x * 256 + threadIdx.x;
    if (t < n) out[t] = f2b(in[t]);
}

// conv_w [CO,E,3,1] -> bf16 layout [co][kh*192+c]
__global__ __launch_bounds__(256) void conv_w_to_bf16(const float* __restrict__ cw,
                                                      ushort* __restrict__ out) {
    int t = blockIdx.x * 256 + threadIdx.x;
    if (t >= COd * 576) return;
    int co = t / 576, rem = t % 576;
    int kh = rem / Ed, c = rem % Ed;
    out[t] = f2b(cw[((size_t)co * Ed + c) * 3 + kh]);
}

// ---------------------------------------------------------------------------
// LayerNorm over E=192, one wave per row, lanes 0..47 hold float4 each.
__global__ __launch_bounds__(256) void ln_kernel(const float* __restrict__ in,
                                                 float* __restrict__ out,
                                                 ushort* __restrict__ outb,
                                                 const float* __restrict__ g,
                                                 const float* __restrict__ bb) {
    int row  = blockIdx.x * 4 + (threadIdx.x >> 6);
    int lane = threadIdx.x & 63;
    bool act = lane < 48;
    float4 v = make_float4(0.f, 0.f, 0.f, 0.f);
    if (act) v = ((const float4*)(in + (size_t)row * Ed))[lane];
    float s = v.x + v.y + v.z + v.w;
    #pragma unroll
    for (int off = 32; off > 0; off >>= 1) s += __shfl_xor(s, off);
    float mu = s * (1.f / 192.f);
    float4 d = make_float4(v.x - mu, v.y - mu, v.z - mu, v.w - mu);
    float qv = act ? (d.x*d.x + d.y*d.y + d.z*d.z + d.w*d.w) : 0.f;
    #pragma unroll
    for (int off = 32; off > 0; off >>= 1) qv += __shfl_xor(qv, off);
    float rstd = rsqrtf(qv * (1.f / 192.f) + 1e-5f);
    if (act) {
        float4 gg  = ((const float4*)g)[lane];
        float4 bbv = ((const float4*)bb)[lane];
        float4 y = make_float4(d.x * rstd * gg.x + bbv.x,
                               d.y * rstd * gg.y + bbv.y,
                               d.z * rstd * gg.z + bbv.z,
                               d.w * rstd * gg.w + bbv.w);
        ((float4*)(out + (size_t)row * Ed))[lane] = y;
        ushort4 yb;
        yb.x = f2b(y.x); yb.y = f2b(y.y); yb.z = f2b(y.z); yb.w = f2b(y.w);
        *(ushort4*)(outb + (size_t)row * Ed + lane * 4) = yb;
    }
}

// ---------------------------------------------------------------------------
// bf16 MFMA GEMM: C[M,N] = A[M,K] @ Wt[N,K]^T + bias (+relu) (+resid)
// BM=128 BN=64 BK=96; 256 threads = 4 waves (2x2). Staging via global_load_lds.
// VOUT: columns >= 384 are V -> written transposed to vtout[bh][d][s] (bf16).
template<int RELU, int RESID, int OBF, int VOUT>
__global__ __launch_bounds__(256) void gemm_mfma(
    const ushort* __restrict__ A, const ushort* __restrict__ Wt,
    const float* __restrict__ bias, const float* __restrict__ resid,
    float* __restrict__ C, ushort* __restrict__ Cb, ushort* __restrict__ vtout,
    int M, int N, int K)
{
    __shared__ __align__(16) ushort As[12288];   // 24 frags (8 msub x 3 ksub) * 1KB
    __shared__ __align__(16) ushort Bs[6144];    // 12 frags (4 nsub x 3 ksub) * 1KB
    const int tid  = threadIdx.x;
    const int lane = tid & 63;
    const int wave = tid >> 6;
    const int wr = wave >> 1, wc = wave & 1;
    const int bm = blockIdx.y * 128;
    const int bn = blockIdx.x * 64;

    const ushort* Ag[6]; ushort* Al[6];
    #pragma unroll
    for (int i = 0; i < 6; ++i) {
        int fa = 4 * i + wave;                 // 0..23
        int msub = fa / 3, ksub = fa % 3;
        int m = msub * 16 + (lane & 15);
        int k = ksub * 32 + ((lane >> 4) << 3);
        Ag[i] = A + (size_t)(bm + m) * K + k;
        Al[i] = As + fa * 512;                 // wave-uniform
    }
    const ushort* Bg[3]; ushort* Bl[3];
    #pragma unroll
    for (int i = 0; i < 3; ++i) {
        int fb = 4 * i + wave;                 // 0..11
        int nsub = fb / 3, ksub = fb % 3;
        int n = nsub * 16 + (lane & 15);
        int k = ksub * 32 + ((lane >> 4) << 3);
        Bg[i] = Wt + (size_t)(bn + n) * K + k;
        Bl[i] = Bs + fb * 512;
    }

    f32x4 acc[4][2];
    #pragma unroll
    for (int i = 0; i < 4; ++i)
        #pragma unroll
        for (int j = 0; j < 2; ++j) acc[i][j] = (f32x4){0.f, 0.f, 0.f, 0.f};

    for (int k0 = 0; k0 < K; k0 += 96) {
        #pragma unroll
        for (int i = 0; i < 6; ++i) gload16(Ag[i] + k0, Al[i], lane);
        #pragma unroll
        for (int i = 0; i < 3; ++i) gload16(Bg[i] + k0, Bl[i], lane);
        __syncthreads();                        // waits vmcnt(0) -> LDS valid
        #pragma unroll
        for (int ksub = 0; ksub < 3; ++ksub) {
            short8 af[4], bf[2];
            #pragma unroll
            for (int ms = 0; ms < 4; ++ms)
                af[ms] = *(const short8*)(As + (((wr*4+ms)*3 + ksub) * 64 + lane) * 8);
            #pragma unroll
            for (int ns = 0; ns < 2; ++ns)
                bf[ns] = *(const short8*)(Bs + (((wc*2+ns)*3 + ksub) * 64 + lane) * 8);
            #pragma unroll
            for (int ms = 0; ms < 4; ++ms)
                #pragma unroll
                for (int ns = 0; ns < 2; ++ns)
                    acc[ms][ns] = __builtin_amdgcn_mfma_f32_16x16x32_bf16(
                        af[ms], bf[ns], acc[ms][ns], 0, 0, 0);
        }
        __syncthreads();
    }

    int q = lane >> 4, colL = lane & 15;
    #pragma unroll
    for (int ms = 0; ms < 4; ++ms) {
        #pragma unroll
        for (int ns = 0; ns < 2; ++ns) {
            int row0 = bm + (wr*4 + ms) * 16 + q * 4;
            int col  = bn + (wc*2 + ns) * 16 + colL;
            float bvv = bias[col];
            float v[4];
            #pragma unroll
            for (int r = 0; r < 4; ++r) {
                v[r] = acc[ms][ns][r] + bvv;
                if (RELU) v[r] = fmaxf(v[r], 0.f);
                if (RESID) v[r] += resid[(size_t)(row0 + r) * N + col];
            }
            if (VOUT && col >= 384) {
                // V column: write transposed to VT[bh][d][s], s=row0..row0+3
                int hh = (col - 384) >> 5, dd = (col - 384) & 31;
                int bidx = row0 >> 9, srow = row0 & 511;
                ushort4 pv;
                pv.x = f2b(v[0]); pv.y = f2b(v[1]); pv.z = f2b(v[2]); pv.w = f2b(v[3]);
                *(ushort4*)(vtout + (((size_t)(bidx * NHd + hh) * 32 + dd) << 9) + srow) = pv;
            } else {
                #pragma unroll
                for (int r = 0; r < 4; ++r) {
                    if (OBF) Cb[(size_t)(row0 + r) * N + col] = f2b(v[r]);
                    else     C [(size_t)(row0 + r) * N + col] = v[r];
                }
            }
        }
    }
}

// ---------------------------------------------------------------------------
// MFMA attention, unshifted softmax, phase-split to expose ILP.
// One wave = 16 q x 512 keys. Per half (8 chunks of 32 keys):
//   phase 1: 8 independent S-chunks (global K loads + QK MFMA + exp) -> packed
//            bf16 P written to wave-private LDS in A-fragment order
//   phase 2: 8 independent PV iterations (ds_read_b128 + V loads + 2 MFMA)
template<int USE_MASK>
__global__ __launch_bounds__(256) void attn_mfma(const ushort* __restrict__ qkv,
                                                 const ushort* __restrict__ vt,
                                                 ushort* __restrict__ att) {
    __shared__ __align__(16) ushort P[4][8][512];    // 32 KB: wave x chunk x frag
    const int bh = blockIdx.x;
    const int b = bh / NHd, h = bh % NHd;
    const int wave = threadIdx.x >> 6, lane = threadIdx.x & 63;
    const int g = lane >> 4, ql = lane & 15;
    const int q0 = blockIdx.y * 64 + wave * 16;
    const int sq = q0 + ql;
    const int qh = blockIdx.y;            // sq>>6 (block 64-aligned)
    const int qw = wave * 16 + ql;        // sq&63
    const float scale = 0.17677669529663687f;   // 1/sqrt(32)

    const ushort* qkbase = qkv + (size_t)b * Ssz * 576;
    short8 qf = *(const short8*)(qkbase + (size_t)sq * 576 + h * 32 + g * 8);
    const ushort* kbase = qkbase + 192 + h * 32;
    const ushort* vbase = vt + (size_t)bh * 32 * 512;
    ushort* pw = &P[wave][0][0];

    // per-lane window masks for the two kw-base cases (multiplicative)
    float pm0[8], pm1[8];
    if (USE_MASK) {
        #pragma unroll
        for (int i = 0; i < 8; ++i) {
            int keyl = (i >> 2) * 16 + 4 * g + (i & 3);
            int dw0 = keyl - qw;      dw0 = dw0 < 0 ? -dw0 : dw0;
            int dw1 = keyl + 32 - qw; dw1 = dw1 < 0 ? -dw1 : dw1;
            pm0[i] = (dw0 <= 5) ? 0.f : 1.f;
            pm1[i] = (dw1 <= 5) ? 0.f : 1.f;
        }
    }

    f32x4 o0 = {0.f,0.f,0.f,0.f}, o1 = {0.f,0.f,0.f,0.f};
    float lacc = 0.f;
    const f32x4 z = {0.f,0.f,0.f,0.f};
    const int wst0 = ((g >> 1) * 16 + ql) * 8 + (g & 1) * 4;        // keys 4g..4g+3
    const int wst1 = (((g >> 1) + 2) * 16 + ql) * 8 + (g & 1) * 4;  // keys 16+4g..

    for (int hf = 0; hf < 2; ++hf) {
        #pragma unroll
        for (int c = 0; c < 8; ++c) {
            const int kt = hf * 8 + c;
            const int kb = kt * 32;
            short8 kf0 = *(const short8*)(kbase + (size_t)(kb + ql) * 576 + g * 8);
            short8 kf1 = *(const short8*)(kbase + (size_t)(kb + 16 + ql) * 576 + g * 8);
            f32x4 st0 = __builtin_amdgcn_mfma_f32_16x16x32_bf16(kf0, qf, z, 0, 0, 0);
            f32x4 st1 = __builtin_amdgcn_mfma_f32_16x16x32_bf16(kf1, qf, z, 0, 0, 0);
            float p[8];
            #pragma unroll
            for (int r = 0; r < 4; ++r) {
                p[r]     = __expf(st0[r] * scale);
                p[4 + r] = __expf(st1[r] * scale);
            }
            if (USE_MASK) {
                int dh = (kt >> 1) - qh; dh = dh < 0 ? -dh : dh;
                if (dh <= 3) {                       // wave-uniform branch
                    const float* pm = (kt & 1) ? pm1 : pm0;
                    #pragma unroll
                    for (int i = 0; i < 8; ++i) p[i] *= pm[i];
                }
            }
            #pragma unroll
            for (int i = 0; i < 8; ++i) lacc += p[i];
            uint u[8];
            #pragma unroll
            for (int i = 0; i < 8; ++i) u[i] = __builtin_bit_cast(uint, p[i]) + 0x8000u;
            uint2 w0, w1;
            w0.x = __builtin_amdgcn_perm(u[1], u[0], 0x07060302u);
            w0.y = __builtin_amdgcn_perm(u[3], u[2], 0x07060302u);
            w1.x = __builtin_amdgcn_perm(u[5], u[4], 0x07060302u);
            w1.y = __builtin_amdgcn_perm(u[7], u[6], 0x07060302u);
            *(uint2*)(pw + c * 512 + wst0) = w0;
            *(uint2*)(pw + c * 512 + wst1) = w1;
        }
        WAIT_LGKM();                              // P writes visible to own wave
        #pragma unroll
        for (int c = 0; c < 8; ++c) {
            const int kb = (hf * 8 + c) * 32;
            short8 paf = *(const short8*)(pw + c * 512 + lane * 8);
            short8 vf0 = *(const short8*)(vbase + (size_t)ql * 512 + kb + 8 * g);
            short8 vf1 = *(const short8*)(vbase + (size_t)(16 + ql) * 512 + kb + 8 * g);
            o0 = __builtin_amdgcn_mfma_f32_16x16x32_bf16(paf, vf0, o0, 0, 0, 0);
            o1 = __builtin_amdgcn_mfma_f32_16x16x32_bf16(paf, vf1, o1, 0, 0, 0);
        }
        WAIT_LGKM();                              // reads done before overwrite
    }
    lacc += __shfl_xor(lacc, 16);
    lacc += __shfl_xor(lacc, 32);
    float inv = 1.f / lacc;
    ushort* op = att + (size_t)b * Ssz * Ed + h * 32;
    #pragma unroll
    for (int r = 0; r < 4; ++r) {
        float iv = __shfl(inv, 4 * g + r);
        int row = q0 + 4 * g + r;
        op[(size_t)row * Ed + ql]      = f2b(o0[r] * iv);
        op[(size_t)row * Ed + 16 + ql] = f2b(o1[r] * iv);
    }
}

// ---------------------------------------------------------------------------
// im2col for merging conv: A2[r=(b*4+ho)*64+w][kh*192+c] = X[b, w*8+2ho+kh-1, c]
__global__ __launch_bounds__(256) void im2col(const float* __restrict__ X,
                                              ushort* __restrict__ A2) {
    int t = blockIdx.x * 256 + threadIdx.x;      // 9437184
    int col = t % 576;
    int r   = t / 576;
    int kh = col / Ed, c = col % Ed;
    int w = r & 63, ho = (r >> 6) & 3, b = r >> 8;
    int hin = 2 * ho + kh - 1;
    float v = 0.f;
    if (hin >= 0 && hin < Himg)
        v = X[((size_t)(b * Ssz + w * Himg + hin)) * Ed + c];
    A2[t] = f2b(v);
}

// ---------------------------------------------------------------------------
// channel LN on conv output C2[r=(b*4+ho)*64+w][co=256] -> out[b,co,ho,w]
__global__ __launch_bounds__(256) void ln_out_kernel(const float* __restrict__ C2,
                                                     const float* __restrict__ g,
                                                     const float* __restrict__ beta,
                                                     float* __restrict__ out) {
    __shared__ float lds[32 * 257];
    int w0 = blockIdx.x * 32, ho = blockIdx.y, b = blockIdx.z;
    int tid = threadIdx.x;
    size_t rbase = ((size_t)b * 4 + ho) * 64 + w0;

    for (int i = 0; i < 32; ++i)
        lds[i * 257 + tid] = C2[(rbase + i) * COd + tid];
    __syncthreads();

    int wv = tid >> 6, lane = tid & 63;
    for (int rr = 0; rr < 8; ++rr) {
        int i = wv * 8 + rr;
        float v0 = lds[i*257 + lane], v1 = lds[i*257 + lane + 64];
        float v2 = lds[i*257 + lane + 128], v3 = lds[i*257 + lane + 192];
        float s = v0 + v1 + v2 + v3;
        #pragma unroll
        for (int off = 32; off > 0; off >>= 1) s += __shfl_xor(s, off);
        float mu = s * (1.f / 256.f);
        float d0 = v0-mu, d1 = v1-mu, d2 = v2-mu, d3 = v3-mu;
        float qv = d0*d0 + d1*d1 + d2*d2 + d3*d3;
        #pragma unroll
        for (int off = 32; off > 0; off >>= 1) qv += __shfl_xor(qv, off);
        float rstd = rsqrtf(qv * (1.f / 256.f) + 1e-5f);
        lds[i*257 + lane]       = d0 * rstd * g[lane]       + beta[lane];
        lds[i*257 + lane + 64]  = d1 * rstd * g[lane + 64]  + beta[lane + 64];
        lds[i*257 + lane + 128] = d2 * rstd * g[lane + 128] + beta[lane + 128];
        lds[i*257 + lane + 192] = d3 * rstd * g[lane + 192] + beta[lane + 192];
    }
    __syncthreads();

    int w = tid & 31, half = tid >> 5;
    for (int j = 0; j < 32; ++j) {
        int co = half + j * 8;
        out[(((size_t)b * COd + co) * 4 + ho) * Wimg + w0 + w] = lds[w * 257 + co];
    }
}

// ---------------------------------------------------------------------------
extern "C" void kernel_launch(void* const* d_in, const int* in_sizes, int n_in,
                              void* d_out, int out_size, void* d_ws, size_t ws_size,
                              hipStream_t stream) {
    const float* image = (const float*)d_in[0];
    const float* in_w  = (const float*)d_in[1];
    const float* in_b  = (const float*)d_in[2];
    const float* out_w = (const float*)d_in[3];
    const float* out_b = (const float*)d_in[4];
    const float* ln1_g = (const float*)d_in[5];
    const float* ln1_b = (const float*)d_in[6];
    const float* ln2_g = (const float*)d_in[7];
    const float* ln2_b = (const float*)d_in[8];
    const float* w1    = (const float*)d_in[9];
    const float* b1    = (const float*)d_in[10];
    const float* w2    = (const float*)d_in[11];
    const float* b2    = (const float*)d_in[12];
    const float* convw = (const float*)d_in[13];
    const float* convb = (const float*)d_in[14];
    const float* mln_g = (const float*)d_in[15];
    const float* mln_b = (const float*)d_in[16];
    float* out = (float*)d_out;
    float* ws  = (float*)d_ws;

    // ws layout (float units) — same as round 4
    float* X    = ws;
    float* XN   = ws + 6291456;
    float* BIG  = ws + 12582912;
    ushort* QKVb = (ushort*)BIG;
    ushort* VT   = (ushort*)(BIG + 9437184);
    ushort* Hb   = (ushort*)BIG;
    ushort* A2b  = (ushort*)BIG;
    float*  C2   = BIG + 4718592;
    ushort* XNb  = (ushort*)(BIG + 12582912);
    ushort* ATTb = (ushort*)(ws + 28311552);
    ushort* Wb   = (ushort*)(ws + 31457280);

    ushort* in_wb  = Wb;                    // 663552
    ushort* out_wb = Wb + 663552;           // 221184
    ushort* w1b    = Wb + 884736;           // 884736
    ushort* w2b    = Wb + 1769472;          // 884736
    ushort* cwb    = Wb + 2654208;          // 147456

    reshape_in<<<Mrows * Ed / 256, 256, 0, stream>>>(image, X);
    f2b_arr<<<(663552 + 255) / 256, 256, 0, stream>>>(in_w,  in_wb,  663552);
    f2b_arr<<<(221184 + 255) / 256, 256, 0, stream>>>(out_w, out_wb, 221184);
    f2b_arr<<<(884736 + 255) / 256, 256, 0, stream>>>(w1,    w1b,    884736);
    f2b_arr<<<(884736 + 255) / 256, 256, 0, stream>>>(w2,    w2b,    884736);
    conv_w_to_bf16<<<(147456 + 255) / 256, 256, 0, stream>>>(convw, cwb);

    for (int i = 0; i < Ld; ++i) {
        ln_kernel<<<Mrows / 4, 256, 0, stream>>>(X, XN, XNb, ln1_g + i*Ed, ln1_b + i*Ed);
        gemm_mfma<0,0,1,1><<<dim3(9, Mrows/128), 256, 0, stream>>>(
            XNb, in_wb + (size_t)i * 3*Ed*Ed, in_b + i * 3*Ed,
            nullptr, nullptr, QKVb, VT, Mrows, 3*Ed, Ed);
        if (i >= 2) attn_mfma<1><<<dim3(Bn * NHd, 8), 256, 0, stream>>>(QKVb, VT, ATTb);
        else        attn_mfma<0><<<dim3(Bn * NHd, 8), 256, 0, stream>>>(QKVb, VT, ATTb);
        gemm_mfma<0,1,0,0><<<dim3(3, Mrows/128), 256, 0, stream>>>(
            ATTb, out_wb + (size_t)i * Ed*Ed, out_b + i*Ed,
            XN, X, nullptr, nullptr, Mrows, Ed, Ed);
        ln_kernel<<<Mrows / 4, 256, 0, stream>>>(X, XN, XNb, ln2_g + i*Ed, ln2_b + i*Ed);
        gemm_mfma<1,0,1,0><<<dim3(12, Mrows/128), 256, 0, stream>>>(
            XNb, w1b + (size_t)i * 4*Ed*Ed, b1 + i * 4*Ed,
            nullptr, nullptr, Hb, nullptr, Mrows, 4*Ed, Ed);
        gemm_mfma<0,1,0,0><<<dim3(3, Mrows/128), 256, 0, stream>>>(
            Hb, w2b + (size_t)i * 4*Ed*Ed, b2 + i*Ed,
            XN, X, nullptr, nullptr, Mrows, Ed, 4*Ed);
    }

    im2col<<<9437184 / 256, 256, 0, stream>>>(X, A2b);
    gemm_mfma<0,0,0,0><<<dim3(4, 16384/128), 256, 0, stream>>>(
        A2b, cwb, convb, nullptr, C2, nullptr, nullptr, 16384, COd, 576);
    ln_out_kernel<<<dim3(2, 4, Bn), 256, 0, stream>>>(C2, mln_g, mln_b, out);
}

// Round 6
// 1429.596 us; speedup vs baseline: 4.0926x; 1.1142x over previous
//
#include <hip/hip_runtime.h>
#include <hip/hip_bf16.h>
#include <math.h>

// Problem constants
#define Bn   64
#define Ssz  512     // W*H = 64*8
#define Ed   192
#define NHd  6
#define HDd  32
#define Ld   6
#define COd  256
#define Himg 8
#define Wimg 64
#define Mrows (Bn*Ssz)   // 32768

typedef unsigned int  uint;
typedef unsigned short ushort;
using short8 = __attribute__((ext_vector_type(8))) short;
using f32x4  = __attribute__((ext_vector_type(4))) float;

#define WAIT_LGKM() __asm__ __volatile__("s_waitcnt lgkmcnt(0)" ::: "memory")

__device__ inline ushort f2b(float f) {          // fp32 -> bf16 RNE
    uint u = __builtin_bit_cast(uint, f);
    u = (u + 0x7FFFu + ((u >> 16) & 1u)) >> 16;
    return (ushort)u;
}
__device__ inline float b2f(uint us) {
    uint v = us << 16;
    return __builtin_bit_cast(float, v);
}

// async global->LDS 16B: lane i lands at lds + i*16 (wave-uniform lds base)
__device__ __forceinline__ void gload16(const ushort* g, ushort* l, int lane) {
#if __has_builtin(__builtin_amdgcn_global_load_lds)
    __builtin_amdgcn_global_load_lds(
        (const __attribute__((address_space(1))) uint*)g,
        (__attribute__((address_space(3))) uint*)l, 16, 0, 0);
#else
    *(uint4*)(l + (size_t)lane * 8) = *(const uint4*)g;
#endif
}

// ---------------------------------------------------------------------------
// reshape: image [B, E, 8, 64] -> X [B, S=w*8+h, E]  (fp32)
__global__ __launch_bounds__(256) void reshape_in(const float* __restrict__ img,
                                                  float* __restrict__ X) {
    int t = blockIdx.x * 256 + threadIdx.x;
    int c = t % Ed;
    int s = (t / Ed) % Ssz;
    int b = t / (Ed * Ssz);
    int w = s >> 3, h = s & 7;
    X[t] = img[(((size_t)b * Ed + c) * Himg + h) * Wimg + w];
}

// ---------------------------------------------------------------------------
__global__ __launch_bounds__(256) void f2b_arr(const float* __restrict__ in,
                                               ushort* __restrict__ out, int n) {
    int t = blockIdx.x * 256 + threadIdx.x;
    if (t < n) out[t] = f2b(in[t]);
}

// conv_w [CO,E,3,1] -> bf16 layout [co][kh*192+c]
__global__ __launch_bounds__(256) void conv_w_to_bf16(const float* __restrict__ cw,
                                                      ushort* __restrict__ out) {
    int t = blockIdx.x * 256 + threadIdx.x;
    if (t >= COd * 576) return;
    int co = t / 576, rem = t % 576;
    int kh = rem / Ed, c = rem % Ed;
    out[t] = f2b(cw[((size_t)co * Ed + c) * 3 + kh]);
}

// ---------------------------------------------------------------------------
// LayerNorm over E=192, one wave per row, lanes 0..47 hold float4 each.
__global__ __launch_bounds__(256) void ln_kernel(const float* __restrict__ in,
                                                 float* __restrict__ out,
                                                 ushort* __restrict__ outb,
                                                 const float* __restrict__ g,
                                                 const float* __restrict__ bb) {
    int row  = blockIdx.x * 4 + (threadIdx.x >> 6);
    int lane = threadIdx.x & 63;
    bool act = lane < 48;
    float4 v = make_float4(0.f, 0.f, 0.f, 0.f);
    if (act) v = ((const float4*)(in + (size_t)row * Ed))[lane];
    float s = v.x + v.y + v.z + v.w;
    #pragma unroll
    for (int off = 32; off > 0; off >>= 1) s += __shfl_xor(s, off);
    float mu = s * (1.f / 192.f);
    float4 d = make_float4(v.x - mu, v.y - mu, v.z - mu, v.w - mu);
    float qv = act ? (d.x*d.x + d.y*d.y + d.z*d.z + d.w*d.w) : 0.f;
    #pragma unroll
    for (int off = 32; off > 0; off >>= 1) qv += __shfl_xor(qv, off);
    float rstd = rsqrtf(qv * (1.f / 192.f) + 1e-5f);
    if (act) {
        float4 gg  = ((const float4*)g)[lane];
        float4 bbv = ((const float4*)bb)[lane];
        float4 y = make_float4(d.x * rstd * gg.x + bbv.x,
                               d.y * rstd * gg.y + bbv.y,
                               d.z * rstd * gg.z + bbv.z,
                               d.w * rstd * gg.w + bbv.w);
        ((float4*)(out + (size_t)row * Ed))[lane] = y;
        ushort4 yb;
        yb.x = f2b(y.x); yb.y = f2b(y.y); yb.z = f2b(y.z); yb.w = f2b(y.w);
        *(ushort4*)(outb + (size_t)row * Ed + lane * 4) = yb;
    }
}

// ---------------------------------------------------------------------------
// bf16 MFMA GEMM: C[M,N] = A[M,K] @ Wt[N,K]^T + bias (+relu) (+resid)
// BM=128 BN=64 BK=96; 256 threads = 4 waves (2x2). Staging via global_load_lds.
// grid = (rowblocks, colblocks): col-blocks sharing an A-tile sit on one XCD.
// VOUT: Q cols -> QP[bh][s][32], K cols -> KP[bh][s][32], V cols -> VT[bh][d][s].
template<int RELU, int RESID, int OBF, int VOUT>
__global__ __launch_bounds__(256) void gemm_mfma(
    const ushort* __restrict__ A, const ushort* __restrict__ Wt,
    const float* __restrict__ bias, const float* __restrict__ resid,
    float* __restrict__ C, ushort* __restrict__ Cb,
    ushort* __restrict__ qpout, ushort* __restrict__ kpout,
    ushort* __restrict__ vtout,
    int M, int N, int K)
{
    __shared__ __align__(16) ushort As[12288];   // 24 frags (8 msub x 3 ksub) * 1KB
    __shared__ __align__(16) ushort Bs[6144];    // 12 frags (4 nsub x 3 ksub) * 1KB
    const int tid  = threadIdx.x;
    const int lane = tid & 63;
    const int wave = tid >> 6;
    const int wr = wave >> 1, wc = wave & 1;
    const int bm = blockIdx.x * 128;
    const int bn = blockIdx.y * 64;

    const ushort* Ag[6]; ushort* Al[6];
    #pragma unroll
    for (int i = 0; i < 6; ++i) {
        int fa = 4 * i + wave;                 // 0..23
        int msub = fa / 3, ksub = fa % 3;
        int m = msub * 16 + (lane & 15);
        int k = ksub * 32 + ((lane >> 4) << 3);
        Ag[i] = A + (size_t)(bm + m) * K + k;
        Al[i] = As + fa * 512;                 // wave-uniform
    }
    const ushort* Bg[3]; ushort* Bl[3];
    #pragma unroll
    for (int i = 0; i < 3; ++i) {
        int fb = 4 * i + wave;                 // 0..11
        int nsub = fb / 3, ksub = fb % 3;
        int n = nsub * 16 + (lane & 15);
        int k = ksub * 32 + ((lane >> 4) << 3);
        Bg[i] = Wt + (size_t)(bn + n) * K + k;
        Bl[i] = Bs + fb * 512;
    }

    f32x4 acc[4][2];
    #pragma unroll
    for (int i = 0; i < 4; ++i)
        #pragma unroll
        for (int j = 0; j < 2; ++j) acc[i][j] = (f32x4){0.f, 0.f, 0.f, 0.f};

    for (int k0 = 0; k0 < K; k0 += 96) {
        #pragma unroll
        for (int i = 0; i < 6; ++i) gload16(Ag[i] + k0, Al[i], lane);
        #pragma unroll
        for (int i = 0; i < 3; ++i) gload16(Bg[i] + k0, Bl[i], lane);
        __syncthreads();                        // waits vmcnt(0) -> LDS valid
        #pragma unroll
        for (int ksub = 0; ksub < 3; ++ksub) {
            short8 af[4], bf[2];
            #pragma unroll
            for (int ms = 0; ms < 4; ++ms)
                af[ms] = *(const short8*)(As + (((wr*4+ms)*3 + ksub) * 64 + lane) * 8);
            #pragma unroll
            for (int ns = 0; ns < 2; ++ns)
                bf[ns] = *(const short8*)(Bs + (((wc*2+ns)*3 + ksub) * 64 + lane) * 8);
            #pragma unroll
            for (int ms = 0; ms < 4; ++ms)
                #pragma unroll
                for (int ns = 0; ns < 2; ++ns)
                    acc[ms][ns] = __builtin_amdgcn_mfma_f32_16x16x32_bf16(
                        af[ms], bf[ns], acc[ms][ns], 0, 0, 0);
        }
        __syncthreads();
    }

    int q = lane >> 4, colL = lane & 15;
    #pragma unroll
    for (int ms = 0; ms < 4; ++ms) {
        #pragma unroll
        for (int ns = 0; ns < 2; ++ns) {
            int row0 = bm + (wr*4 + ms) * 16 + q * 4;
            int col  = bn + (wc*2 + ns) * 16 + colL;
            float bvv = bias[col];
            float v[4];
            #pragma unroll
            for (int r = 0; r < 4; ++r) {
                v[r] = acc[ms][ns][r] + bvv;
                if (RELU) v[r] = fmaxf(v[r], 0.f);
                if (RESID) v[r] += resid[(size_t)(row0 + r) * N + col];
            }
            if (VOUT) {
                int bidx = row0 >> 9, srow = row0 & 511;
                if (col >= 384) {                 // V -> VT[bh][d][s]
                    int hh = (col - 384) >> 5, dd = (col - 384) & 31;
                    ushort4 pv;
                    pv.x = f2b(v[0]); pv.y = f2b(v[1]); pv.z = f2b(v[2]); pv.w = f2b(v[3]);
                    *(ushort4*)(vtout + (((size_t)(bidx * NHd + hh) * 32 + dd) << 9) + srow) = pv;
                } else {                          // Q/K -> {QP,KP}[bh][s][32]
                    ushort* dst = (col < 192) ? qpout : kpout;
                    int cc = (col < 192) ? col : col - 192;
                    int hh = cc >> 5, dd = cc & 31;
                    ushort* p = dst + ((size_t)(bidx * NHd + hh) << 14) + (size_t)srow * 32 + dd;
                    p[0]  = f2b(v[0]); p[32] = f2b(v[1]);
                    p[64] = f2b(v[2]); p[96] = f2b(v[3]);
                }
            } else {
                #pragma unroll
                for (int r = 0; r < 4; ++r) {
                    if (OBF) Cb[(size_t)(row0 + r) * N + col] = f2b(v[r]);
                    else     C [(size_t)(row0 + r) * N + col] = v[r];
                }
            }
        }
    }
}

// ---------------------------------------------------------------------------
// MFMA attention over packed per-head QP/KP[bh][s][32], VT[bh][d][s].
// Unshifted softmax; one wave = 16 q x 512 keys; 4-chunk ILP groups with
// wave-private LDS P staging (16 KB/block). All global reads coalesced.
template<int USE_MASK>
__global__ __launch_bounds__(256) void attn_mfma(const ushort* __restrict__ qp,
                                                 const ushort* __restrict__ kp,
                                                 const ushort* __restrict__ vt,
                                                 ushort* __restrict__ att) {
    __shared__ __align__(16) ushort P[4][4][512];    // 16 KB: wave x chunk x frag
    const int bh = blockIdx.x;
    const int b = bh / NHd, h = bh % NHd;
    const int wave = threadIdx.x >> 6, lane = threadIdx.x & 63;
    const int g = lane >> 4, ql = lane & 15;
    const int q0 = blockIdx.y * 64 + wave * 16;      // q row in [0,512)
    const int sq = q0 + ql;
    const int qh = blockIdx.y;            // sq>>6 (block 64-aligned)
    const int qw = wave * 16 + ql;        // sq&63
    const float scale = 0.17677669529663687f;   // 1/sqrt(32)

    const ushort* qbase = qp + ((size_t)bh << 14);
    const ushort* kbase = kp + ((size_t)bh << 14);
    const ushort* vbase = vt + ((size_t)bh << 14);
    short8 qf = *(const short8*)(qbase + (size_t)sq * 32 + g * 8);
    ushort* pw = &P[wave][0][0];

    // per-lane window masks for the two kw-base cases (multiplicative)
    float pm0[8], pm1[8];
    if (USE_MASK) {
        #pragma unroll
        for (int i = 0; i < 8; ++i) {
            int keyl = (i >> 2) * 16 + 4 * g + (i & 3);
            int dw0 = keyl - qw;      dw0 = dw0 < 0 ? -dw0 : dw0;
            int dw1 = keyl + 32 - qw; dw1 = dw1 < 0 ? -dw1 : dw1;
            pm0[i] = (dw0 <= 5) ? 0.f : 1.f;
            pm1[i] = (dw1 <= 5) ? 0.f : 1.f;
        }
    }

    f32x4 o0 = {0.f,0.f,0.f,0.f}, o1 = {0.f,0.f,0.f,0.f};
    float lacc = 0.f;
    const f32x4 z = {0.f,0.f,0.f,0.f};
    const int wst0 = ((g >> 1) * 16 + ql) * 8 + (g & 1) * 4;        // keys 4g..4g+3
    const int wst1 = (((g >> 1) + 2) * 16 + ql) * 8 + (g & 1) * 4;  // keys 16+4g..

    for (int grp = 0; grp < 4; ++grp) {
        #pragma unroll
        for (int c = 0; c < 4; ++c) {
            const int kt = grp * 4 + c;
            const int kb = kt * 32;
            short8 kf0 = *(const short8*)(kbase + (size_t)(kb + ql) * 32 + g * 8);
            short8 kf1 = *(const short8*)(kbase + (size_t)(kb + 16 + ql) * 32 + g * 8);
            f32x4 st0 = __builtin_amdgcn_mfma_f32_16x16x32_bf16(kf0, qf, z, 0, 0, 0);
            f32x4 st1 = __builtin_amdgcn_mfma_f32_16x16x32_bf16(kf1, qf, z, 0, 0, 0);
            float p[8];
            #pragma unroll
            for (int r = 0; r < 4; ++r) {
                p[r]     = __expf(st0[r] * scale);
                p[4 + r] = __expf(st1[r] * scale);
            }
            if (USE_MASK) {
                int dh = (kt >> 1) - qh; dh = dh < 0 ? -dh : dh;
                if (dh <= 3) {                       // wave-uniform branch
                    const float* pm = (kt & 1) ? pm1 : pm0;
                    #pragma unroll
                    for (int i = 0; i < 8; ++i) p[i] *= pm[i];
                }
            }
            #pragma unroll
            for (int i = 0; i < 8; ++i) lacc += p[i];
            uint u[8];
            #pragma unroll
            for (int i = 0; i < 8; ++i) u[i] = __builtin_bit_cast(uint, p[i]) + 0x8000u;
            uint2 w0, w1;
            w0.x = __builtin_amdgcn_perm(u[1], u[0], 0x07060302u);
            w0.y = __builtin_amdgcn_perm(u[3], u[2], 0x07060302u);
            w1.x = __builtin_amdgcn_perm(u[5], u[4], 0x07060302u);
            w1.y = __builtin_amdgcn_perm(u[7], u[6], 0x07060302u);
            *(uint2*)(pw + c * 512 + wst0) = w0;
            *(uint2*)(pw + c * 512 + wst1) = w1;
        }
        WAIT_LGKM();                              // P writes visible to own wave
        #pragma unroll
        for (int c = 0; c < 4; ++c) {
            const int kb = (grp * 4 + c) * 32;
            short8 paf = *(const short8*)(pw + c * 512 + lane * 8);
            short8 vf0 = *(const short8*)(vbase + (size_t)ql * 512 + kb + 8 * g);
            short8 vf1 = *(const short8*)(vbase + (size_t)(16 + ql) * 512 + kb + 8 * g);
            o0 = __builtin_amdgcn_mfma_f32_16x16x32_bf16(paf, vf0, o0, 0, 0, 0);
            o1 = __builtin_amdgcn_mfma_f32_16x16x32_bf16(paf, vf1, o1, 0, 0, 0);
        }
        WAIT_LGKM();                              // reads done before overwrite
    }
    lacc += __shfl_xor(lacc, 16);
    lacc += __shfl_xor(lacc, 32);
    float inv = 1.f / lacc;
    ushort* op = att + (size_t)b * Ssz * Ed + h * 32;
    #pragma unroll
    for (int r = 0; r < 4; ++r) {
        float iv = __shfl(inv, 4 * g + r);
        int row = q0 + 4 * g + r;
        op[(size_t)row * Ed + ql]      = f2b(o0[r] * iv);
        op[(size_t)row * Ed + 16 + ql] = f2b(o1[r] * iv);
    }
}

// ---------------------------------------------------------------------------
// im2col for merging conv: A2[r=(b*4+ho)*64+w][kh*192+c] = X[b, w*8+2ho+kh-1, c]
__global__ __launch_bounds__(256) void im2col(const float* __restrict__ X,
                                              ushort* __restrict__ A2) {
    int t = blockIdx.x * 256 + threadIdx.x;      // 9437184
    int col = t % 576;
    int r   = t / 576;
    int kh = col / Ed, c = col % Ed;
    int w = r & 63, ho = (r >> 6) & 3, b = r >> 8;
    int hin = 2 * ho + kh - 1;
    float v = 0.f;
    if (hin >= 0 && hin < Himg)
        v = X[((size_t)(b * Ssz + w * Himg + hin)) * Ed + c];
    A2[t] = f2b(v);
}

// ---------------------------------------------------------------------------
// channel LN on conv output C2[r=(b*4+ho)*64+w][co=256] -> out[b,co,ho,w]
__global__ __launch_bounds__(256) void ln_out_kernel(const float* __restrict__ C2,
                                                     const float* __restrict__ g,
                                                     const float* __restrict__ beta,
                                                     float* __restrict__ out) {
    __shared__ float lds[32 * 257];
    int w0 = blockIdx.x * 32, ho = blockIdx.y, b = blockIdx.z;
    int tid = threadIdx.x;
    size_t rbase = ((size_t)b * 4 + ho) * 64 + w0;

    for (int i = 0; i < 32; ++i)
        lds[i * 257 + tid] = C2[(rbase + i) * COd + tid];
    __syncthreads();

    int wv = tid >> 6, lane = tid & 63;
    for (int rr = 0; rr < 8; ++rr) {
        int i = wv * 8 + rr;
        float v0 = lds[i*257 + lane], v1 = lds[i*257 + lane + 64];
        float v2 = lds[i*257 + lane + 128], v3 = lds[i*257 + lane + 192];
        float s = v0 + v1 + v2 + v3;
        #pragma unroll
        for (int off = 32; off > 0; off >>= 1) s += __shfl_xor(s, off);
        float mu = s * (1.f / 256.f);
        float d0 = v0-mu, d1 = v1-mu, d2 = v2-mu, d3 = v3-mu;
        float qv = d0*d0 + d1*d1 + d2*d2 + d3*d3;
        #pragma unroll
        for (int off = 32; off > 0; off >>= 1) qv += __shfl_xor(qv, off);
        float rstd = rsqrtf(qv * (1.f / 256.f) + 1e-5f);
        lds[i*257 + lane]       = d0 * rstd * g[lane]       + beta[lane];
        lds[i*257 + lane + 64]  = d1 * rstd * g[lane + 64]  + beta[lane + 64];
        lds[i*257 + lane + 128] = d2 * rstd * g[lane + 128] + beta[lane + 128];
        lds[i*257 + lane + 192] = d3 * rstd * g[lane + 192] + beta[lane + 192];
    }
    __syncthreads();

    int w = tid & 31, half = tid >> 5;
    for (int j = 0; j < 32; ++j) {
        int co = half + j * 8;
        out[(((size_t)b * COd + co) * 4 + ho) * Wimg + w0 + w] = lds[w * 257 + co];
    }
}

// ---------------------------------------------------------------------------
extern "C" void kernel_launch(void* const* d_in, const int* in_sizes, int n_in,
                              void* d_out, int out_size, void* d_ws, size_t ws_size,
                              hipStream_t stream) {
    const float* image = (const float*)d_in[0];
    const float* in_w  = (const float*)d_in[1];
    const float* in_b  = (const float*)d_in[2];
    const float* out_w = (const float*)d_in[3];
    const float* out_b = (const float*)d_in[4];
    const float* ln1_g = (const float*)d_in[5];
    const float* ln1_b = (const float*)d_in[6];
    const float* ln2_g = (const float*)d_in[7];
    const float* ln2_b = (const float*)d_in[8];
    const float* w1    = (const float*)d_in[9];
    const float* b1    = (const float*)d_in[10];
    const float* w2    = (const float*)d_in[11];
    const float* b2    = (const float*)d_in[12];
    const float* convw = (const float*)d_in[13];
    const float* convb = (const float*)d_in[14];
    const float* mln_g = (const float*)d_in[15];
    const float* mln_b = (const float*)d_in[16];
    float* out = (float*)d_out;
    float* ws  = (float*)d_ws;

    // ws layout (float units):
    //  X    [0, 6291456)
    //  XN   [6291456, 12582912)
    //  BIG  [12582912, 28311552):
    //       QP bf16 @BIG (3145728 f) | KP @+3145728 | VT @+6291456  (tot 9437184 f)
    //       Hb bf16 (12582912 f, clobbers QP/KP/VT after attention)
    //       A2b bf16 @BIG + C2 f32 @BIG+4718592 (conv path, end)
    //  XNb  bf16 @ BIG+12582912  [25165824, 28311552)
    //  ATTb bf16 [28311552, 31457280)
    //  Wb   bf16 [31457280, 32858112)
    float* X    = ws;
    float* XN   = ws + 6291456;
    float* BIG  = ws + 12582912;
    ushort* QP   = (ushort*)BIG;
    ushort* KP   = (ushort*)(BIG + 3145728);
    ushort* VT   = (ushort*)(BIG + 6291456);
    ushort* Hb   = (ushort*)BIG;
    ushort* A2b  = (ushort*)BIG;
    float*  C2   = BIG + 4718592;
    ushort* XNb  = (ushort*)(BIG + 12582912);
    ushort* ATTb = (ushort*)(ws + 28311552);
    ushort* Wb   = (ushort*)(ws + 31457280);

    ushort* in_wb  = Wb;                    // 663552
    ushort* out_wb = Wb + 663552;           // 221184
    ushort* w1b    = Wb + 884736;           // 884736
    ushort* w2b    = Wb + 1769472;          // 884736
    ushort* cwb    = Wb + 2654208;          // 147456

    reshape_in<<<Mrows * Ed / 256, 256, 0, stream>>>(image, X);
    f2b_arr<<<(663552 + 255) / 256, 256, 0, stream>>>(in_w,  in_wb,  663552);
    f2b_arr<<<(221184 + 255) / 256, 256, 0, stream>>>(out_w, out_wb, 221184);
    f2b_arr<<<(884736 + 255) / 256, 256, 0, stream>>>(w1,    w1b,    884736);
    f2b_arr<<<(884736 + 255) / 256, 256, 0, stream>>>(w2,    w2b,    884736);
    conv_w_to_bf16<<<(147456 + 255) / 256, 256, 0, stream>>>(convw, cwb);

    for (int i = 0; i < Ld; ++i) {
        ln_kernel<<<Mrows / 4, 256, 0, stream>>>(X, XN, XNb, ln1_g + i*Ed, ln1_b + i*Ed);
        gemm_mfma<0,0,1,1><<<dim3(Mrows/128, 9), 256, 0, stream>>>(
            XNb, in_wb + (size_t)i * 3*Ed*Ed, in_b + i * 3*Ed,
            nullptr, nullptr, nullptr, QP, KP, VT, Mrows, 3*Ed, Ed);
        if (i >= 2) attn_mfma<1><<<dim3(Bn * NHd, 8), 256, 0, stream>>>(QP, KP, VT, ATTb);
        else        attn_mfma<0><<<dim3(Bn * NHd, 8), 256, 0, stream>>>(QP, KP, VT, ATTb);
        gemm_mfma<0,1,0,0><<<dim3(Mrows/128, 3), 256, 0, stream>>>(
            ATTb, out_wb + (size_t)i * Ed*Ed, out_b + i*Ed,
            XN, X, nullptr, nullptr, nullptr, nullptr, Mrows, Ed, Ed);
        ln_kernel<<<Mrows / 4, 256, 0, stream>>>(X, XN, XNb, ln2_g + i*Ed, ln2_b + i*Ed);
        gemm_mfma<1,0,1,0><<<dim3(Mrows/128, 12), 256, 0, stream>>>(
            XNb, w1b + (size_t)i * 4*Ed*Ed, b1 + i * 4*Ed,
            nullptr, nullptr, Hb, nullptr, nullptr, nullptr, Mrows, 4*Ed, Ed);
        gemm_mfma<0,1,0,0><<<dim3(Mrows/128, 3), 256, 0, stream>>>(
            Hb, w2b + (size_t)i * 4*Ed*Ed, b2 + i*Ed,
            XN, X, nullptr, nullptr, nullptr, nullptr, Mrows, Ed, 4*Ed);
    }

    im2col<<<9437184 / 256, 256, 0, stream>>>(X, A2b);
    gemm_mfma<0,0,0,0><<<dim3(16384/128, 4), 256, 0, stream>>>(
        A2b, cwb, convb, nullptr, C2, nullptr, nullptr, nullptr, nullptr,
        16384, COd, 576);
    ln_out_kernel<<<dim3(2, 4, Bn), 256, 0, stream>>>(C2, mln_g, mln_b, out);
}